// Round 1
// 1588.824 us; speedup vs baseline: 1.2148x; 1.2148x over previous
//
#include <hip/hip_runtime.h>

typedef unsigned short ushort_t;
typedef unsigned int uint_t;

#define N_NODES 65536
#define N_EDGES 262144

typedef __attribute__((ext_vector_type(8))) short bf16x8;
typedef __attribute__((ext_vector_type(4))) float f32x4;

// ---------- bf16 helpers ----------
__device__ __forceinline__ ushort_t f2b(float x) {
  uint_t u = __float_as_uint(x);
  u += 0x7fffu + ((u >> 16) & 1u);  // RNE
  return (ushort_t)(u >> 16);
}
__device__ __forceinline__ void dec8(uint4 v, float* f) {
  f[0] = __uint_as_float(v.x << 16); f[1] = __uint_as_float(v.x & 0xffff0000u);
  f[2] = __uint_as_float(v.y << 16); f[3] = __uint_as_float(v.y & 0xffff0000u);
  f[4] = __uint_as_float(v.z << 16); f[5] = __uint_as_float(v.z & 0xffff0000u);
  f[6] = __uint_as_float(v.w << 16); f[7] = __uint_as_float(v.w & 0xffff0000u);
}
__device__ __forceinline__ void dec4(uint2 v, float* f) {
  f[0] = __uint_as_float(v.x << 16); f[1] = __uint_as_float(v.x & 0xffff0000u);
  f[2] = __uint_as_float(v.y << 16); f[3] = __uint_as_float(v.y & 0xffff0000u);
}
__device__ __forceinline__ uint4 enc8(const float* f) {
  uint4 v;
  v.x = (uint_t)f2b(f[0]) | ((uint_t)f2b(f[1]) << 16);
  v.y = (uint_t)f2b(f[2]) | ((uint_t)f2b(f[3]) << 16);
  v.z = (uint_t)f2b(f[4]) | ((uint_t)f2b(f[5]) << 16);
  v.w = (uint_t)f2b(f[6]) | ((uint_t)f2b(f[7]) << 16);
  return v;
}
__device__ __forceinline__ uint2 enc4(const float* f) {
  uint2 v;
  v.x = (uint_t)f2b(f[0]) | ((uint_t)f2b(f[1]) << 16);
  v.y = (uint_t)f2b(f[2]) | ((uint_t)f2b(f[3]) << 16);
  return v;
}
__device__ __forceinline__ void ld8(const float* p, float* f) {
  float4 v0 = *(const float4*)p;
  float4 v1 = *(const float4*)(p + 4);
  f[0]=v0.x; f[1]=v0.y; f[2]=v0.z; f[3]=v0.w;
  f[4]=v1.x; f[5]=v1.y; f[6]=v1.z; f[7]=v1.w;
}

#define ELUF(v) ((v) > 0.f ? (v) : __expf(v) - 1.f)

// async global->LDS, 16B per lane; lds base must be wave-uniform (lane deposits at base+lane*16)
__device__ __forceinline__ void async16(void* lds, const void* g) {
  __builtin_amdgcn_global_load_lds(
      (const __attribute__((address_space(1))) void*)g,
      (__attribute__((address_space(3))) void*)lds, 16, 0, 0);
}

// ---------- weight transpose+cvt: dst[m][n*K+k] = bf16(src[m][k*N+n]) ----------
__global__ void wt_kernel(const float* __restrict__ src, ushort_t* __restrict__ dst,
                          int K, int N) {
  long m = blockIdx.y;
  long base = m * (long)K * N;
  int tid = blockIdx.x * 256 + threadIdx.x;
  if (tid >= K * N) return;
  int k = tid % K, n = tid / K;
  dst[base + (long)n * K + k] = f2b(src[base + (long)k * N + n]);
}

// ---------- MFMA GEMM: outb[rows][256] = bf16( A_f32[rows][K] @ Wt^T ), Wt bf16 [256][K] ----------
__global__ __launch_bounds__(256, 2) void gemm_mfma(
    const float* __restrict__ A, const ushort_t* __restrict__ Wt,
    ushort_t* __restrict__ outb, int K) {
  __shared__ __align__(16) char smem[4096 + 16384];
  ushort_t (*sA)[32] = (ushort_t(*)[32])smem;           // [64][32] bf16
  ushort_t (*sB)[32] = (ushort_t(*)[32])(smem + 4096);  // [256][32] bf16
  int t = threadIdx.x, w = t >> 6, l = t & 63;
  long r0 = (long)blockIdx.x * 64;
  f32x4 zero = {0.f, 0.f, 0.f, 0.f};
  f32x4 acc[4][4];
#pragma unroll
  for (int mt = 0; mt < 4; ++mt)
#pragma unroll
    for (int nt = 0; nt < 4; ++nt) acc[mt][nt] = zero;

  for (int kc = 0; kc < K / 32; ++kc) {
    __syncthreads();
    {  // stage A (f32 -> bf16)
      int r = t >> 2, ks8 = (t & 3) * 8;
      float f[8]; ld8(A + (r0 + r) * (long)K + kc * 32 + ks8, f);
      *(uint4*)&sA[r][ks8] = enc8(f);
    }
#pragma unroll
    for (int j = 0; j < 4; ++j) {  // stage B async
      int u = (w * 4 + j) * 64 + l;
      int n = u >> 2, ks = u & 3;
      async16((char*)sB + (w * 4 + j) * 1024, Wt + (long)n * K + kc * 32 + ks * 8);
    }
    __syncthreads();
    bf16x8 af[4], bf[4];
#pragma unroll
    for (int mt = 0; mt < 4; ++mt)
      af[mt] = *(const bf16x8*)&sA[mt * 16 + (l & 15)][(l >> 4) * 8];
#pragma unroll
    for (int nt = 0; nt < 4; ++nt)
      bf[nt] = *(const bf16x8*)&sB[w * 64 + nt * 16 + (l & 15)][(l >> 4) * 8];
#pragma unroll
    for (int mt = 0; mt < 4; ++mt)
#pragma unroll
      for (int nt = 0; nt < 4; ++nt)
        acc[mt][nt] = __builtin_amdgcn_mfma_f32_16x16x32_bf16(af[mt], bf[nt], acc[mt][nt], 0, 0, 0);
  }
#pragma unroll
  for (int mt = 0; mt < 4; ++mt)
#pragma unroll
    for (int nt = 0; nt < 4; ++nt)
#pragma unroll
      for (int i = 0; i < 4; ++i) {
        long row = r0 + mt * 16 + (l >> 4) * 4 + i;
        int col = w * 64 + nt * 16 + (l & 15);
        outb[row * 256 + col] = f2b(acc[mt][nt][i]);
      }
}

// ---------- eproj GEMM: eproj[rows][256] = bf16(edges @ W_nb), + fused sed[rows][4] = edges . a_edge^T
// A bf16 [rows][256], Wt bf16 [256 n=h*64+p][256 k]; score via extra MFMA on wave 0.
__global__ __launch_bounds__(256, 2) void gemm_eproj(
    const ushort_t* __restrict__ A, const ushort_t* __restrict__ Wt,
    const float* __restrict__ a_edge,  // f32 [4][256]
    ushort_t* __restrict__ outb, float* __restrict__ sed) {
  __shared__ __align__(16) char smem[4096 + 16384 + 8192];
  ushort_t (*sA)[32]   = (ushort_t(*)[32])smem;            // [64][32]
  ushort_t (*sB)[32]   = (ushort_t(*)[32])(smem + 4096);   // [256][32]
  ushort_t (*sAe)[256] = (ushort_t(*)[256])(smem + 20480); // [16][256], rows 4..15 zero
  int t = threadIdx.x, w = t >> 6, l = t & 63;
  long r0 = (long)blockIdx.x * 64;

  {  // stage a_edge^T as B-layout tile (16 cols, cols>=4 zero)
    int row = t >> 4, seg = (t & 15) * 16;
    float f[16];
    if (row < 4) {
      ld8(a_edge + row * 256 + seg, f);
      ld8(a_edge + row * 256 + seg + 8, f + 8);
    } else {
#pragma unroll
      for (int i = 0; i < 16; ++i) f[i] = 0.f;
    }
    *(uint4*)&sAe[row][seg] = enc8(f);
    *(uint4*)&sAe[row][seg + 8] = enc8(f + 8);
  }

  f32x4 zero = {0.f, 0.f, 0.f, 0.f};
  f32x4 acc[4][4];
  f32x4 accs[4];
#pragma unroll
  for (int mt = 0; mt < 4; ++mt) {
    accs[mt] = zero;
#pragma unroll
    for (int nt = 0; nt < 4; ++nt) acc[mt][nt] = zero;
  }

  for (int kc = 0; kc < 8; ++kc) {
    __syncthreads();
    // stage A (already bf16): one 16B async per thread
    async16((char*)sA + w * 1024, A + (r0 + (t >> 2)) * 256 + kc * 32 + (t & 3) * 8);
#pragma unroll
    for (int j = 0; j < 4; ++j) {  // stage B
      int u = (w * 4 + j) * 64 + l;
      int n = u >> 2, ks = u & 3;
      async16((char*)sB + (w * 4 + j) * 1024, Wt + (long)n * 256 + kc * 32 + ks * 8);
    }
    __syncthreads();
    bf16x8 af[4], bf[4];
#pragma unroll
    for (int mt = 0; mt < 4; ++mt)
      af[mt] = *(const bf16x8*)&sA[mt * 16 + (l & 15)][(l >> 4) * 8];
#pragma unroll
    for (int nt = 0; nt < 4; ++nt)
      bf[nt] = *(const bf16x8*)&sB[w * 64 + nt * 16 + (l & 15)][(l >> 4) * 8];
#pragma unroll
    for (int mt = 0; mt < 4; ++mt)
#pragma unroll
      for (int nt = 0; nt < 4; ++nt)
        acc[mt][nt] = __builtin_amdgcn_mfma_f32_16x16x32_bf16(af[mt], bf[nt], acc[mt][nt], 0, 0, 0);
    if (w == 0) {  // fused edge scores: A @ a_edge^T
      bf16x8 bs = *(const bf16x8*)&sAe[l & 15][kc * 32 + (l >> 4) * 8];
#pragma unroll
      for (int mt = 0; mt < 4; ++mt)
        accs[mt] = __builtin_amdgcn_mfma_f32_16x16x32_bf16(af[mt], bs, accs[mt], 0, 0, 0);
    }
  }
#pragma unroll
  for (int mt = 0; mt < 4; ++mt)
#pragma unroll
    for (int nt = 0; nt < 4; ++nt)
#pragma unroll
      for (int i = 0; i < 4; ++i) {
        long row = r0 + mt * 16 + (l >> 4) * 4 + i;
        int col = w * 64 + nt * 16 + (l & 15);
        outb[row * 256 + col] = f2b(acc[mt][nt][i]);
      }
  if (w == 0 && (l & 15) < 4) {
#pragma unroll
    for (int mt = 0; mt < 4; ++mt)
#pragma unroll
      for (int i = 0; i < 4; ++i) {
        long row = r0 + mt * 16 + (l >> 4) * 4 + i;
        sed[row * 4 + (l & 15)] = accs[mt][i];
      }
  }
}

// ---------- edge aggregator (L0 only), MFMA projection, wave = head ----------
__global__ __launch_bounds__(256, 2) void edge_kernel(
    const ushort_t* __restrict__ xb,   // base bf16 [N][256]
    const ushort_t* __restrict__ ein,  // bf16 [E][256]
    ushort_t* __restrict__ eout,       // bf16 [E][256]
    const int* __restrict__ ena,       // [E][2]
    const float* __restrict__ a_n, const float* __restrict__ a_e,  // [4][256]
    const ushort_t* __restrict__ Wt) { // bf16 [256 n=h*64+p][256 k]
  __shared__ __align__(16) char smem[8192 + 16384 + 4096 + 1024 + 256 + 16];
  ushort_t (*sY)[32][32] = (ushort_t(*)[32][32])smem;         // [4][32][32]
  ushort_t (*sB)[32]     = (ushort_t(*)[32])(smem + 8192);    // [256][32]
  ushort_t (*sAf)[256]   = (ushort_t(*)[256])(smem + 24576);  // [8][256]  (a_n 0-3, a_e 4-7)
  float    (*sAlp)[4][2] = (float(*)[4][2])(smem + 28672);    // [32][4][2]
  int* sIdx              = (int*)(smem + 29696);              // [64]  q*32+e
  ushort_t* sOut         = (ushort_t*)smem;                   // overlay [32][264] (16896B <= 24576)

  int t = threadIdx.x, w = t >> 6, l = t & 63;
  long e0 = (long)blockIdx.x * 32;

  if (t < 64) sIdx[(t & 1) * 32 + (t >> 1)] = ena[(e0 + (t >> 1)) * 2 + (t & 1)];
  {  // stage a_n/a_e as bf16
    int row = t >> 5, dof = (t & 31) * 8;
    const float* src = (row < 4 ? a_n + row * 256 : a_e + (row - 4) * 256) + dof;
    float f[8]; ld8(src, f);
    *(uint4*)&sAf[row][dof] = enc8(f);
  }
  __syncthreads();

  int eT = t >> 3, sT = t & 7;
  int nid0 = sIdx[eT], nid1 = sIdx[32 + eT];
  const ushort_t* pxe = ein + (e0 + eT) * 256;
  const ushort_t* px0 = xb + (long)nid0 * 256;
  const ushort_t* px1 = xb + (long)nid1 * 256;

  // ---- attention scores (direct global reads of gathered rows; 8 threads/edge) ----
  float an0[4] = {0,0,0,0}, an1[4] = {0,0,0,0}, aee[4] = {0,0,0,0};
#pragma unroll
  for (int kc = 0; kc < 8; ++kc) {
    int dof = kc * 32 + sT * 4;
    float xe[4], x0[4], x1[4];
    dec4(*(const uint2*)(pxe + dof), xe);
    dec4(*(const uint2*)(px0 + dof), x0);
    dec4(*(const uint2*)(px1 + dof), x1);
#pragma unroll
    for (int h = 0; h < 4; ++h) {
      float av[4], bv[4];
      dec4(*(const uint2*)&sAf[h][dof], av);
      dec4(*(const uint2*)&sAf[4 + h][dof], bv);
#pragma unroll
      for (int d = 0; d < 4; ++d) {
        an0[h] += x0[d] * av[d];
        an1[h] += x1[d] * av[d];
        aee[h] += xe[d] * bv[d];
      }
    }
  }
#pragma unroll
  for (int m = 1; m <= 4; m <<= 1)
#pragma unroll
    for (int h = 0; h < 4; ++h) {
      an0[h] += __shfl_xor(an0[h], m, 64);
      an1[h] += __shfl_xor(an1[h], m, 64);
      aee[h] += __shfl_xor(aee[h], m, 64);
    }
  if (sT == 0) {
#pragma unroll
    for (int h = 0; h < 4; ++h) {
      float s0 = an0[h] + aee[h]; s0 = s0 > 0.f ? s0 : 0.2f * s0;
      float s1 = an1[h] + aee[h]; s1 = s1 > 0.f ? s1 : 0.2f * s1;
      float mx = fmaxf(s0, s1);
      float g0 = __expf(s0 - mx), g1 = __expf(s1 - mx);
      float inv = 1.f / (g0 + g1);
      sAlp[eT][h][0] = g0 * inv;
      sAlp[eT][h][1] = g1 * inv;
    }
  }
  __syncthreads();
  float alp[4][2];
#pragma unroll
  for (int h = 0; h < 4; ++h) {
    alp[h][0] = sAlp[eT][h][0];
    alp[h][1] = sAlp[eT][h][1];
  }

  f32x4 zero = {0.f, 0.f, 0.f, 0.f};
  f32x4 acc[2][4];
#pragma unroll
  for (int mt = 0; mt < 2; ++mt)
#pragma unroll
    for (int nt = 0; nt < 4; ++nt) acc[mt][nt] = zero;

  int ks4 = sT * 4;
  for (int kc = 0; kc < 8; ++kc) {
    __syncthreads();
#pragma unroll
    for (int j = 0; j < 4; ++j) {  // stage Wt chunk
      int u = (w * 4 + j) * 64 + l;
      int n = u >> 2, ks = u & 3;
      async16((char*)sB + (w * 4 + j) * 1024, Wt + (long)n * 256 + kc * 32 + ks * 8);
    }
    {  // build Y = ein + a0*x0 + a1*x1 per head (bf16 into sY)
      int dof = kc * 32 + ks4;
      float xe[4], x0[4], x1[4];
      dec4(*(const uint2*)(pxe + dof), xe);
      dec4(*(const uint2*)(px0 + dof), x0);
      dec4(*(const uint2*)(px1 + dof), x1);
#pragma unroll
      for (int h = 0; h < 4; ++h) {
        float y[4];
#pragma unroll
        for (int d = 0; d < 4; ++d)
          y[d] = xe[d] + alp[h][0] * x0[d] + alp[h][1] * x1[d];
        *(uint2*)&sY[h][eT][ks4] = enc4(y);
      }
    }
    __syncthreads();
    bf16x8 af[2], bf[4];
#pragma unroll
    for (int mt = 0; mt < 2; ++mt)
      af[mt] = *(const bf16x8*)&sY[w][mt * 16 + (l & 15)][(l >> 4) * 8];
#pragma unroll
    for (int nt = 0; nt < 4; ++nt)
      bf[nt] = *(const bf16x8*)&sB[w * 64 + nt * 16 + (l & 15)][(l >> 4) * 8];
#pragma unroll
    for (int mt = 0; mt < 2; ++mt)
#pragma unroll
      for (int nt = 0; nt < 4; ++nt)
        acc[mt][nt] = __builtin_amdgcn_mfma_f32_16x16x32_bf16(af[mt], bf[nt], acc[mt][nt], 0, 0, 0);
  }
  __syncthreads();
#pragma unroll
  for (int mt = 0; mt < 2; ++mt)
#pragma unroll
    for (int nt = 0; nt < 4; ++nt)
#pragma unroll
      for (int i = 0; i < 4; ++i) {
        int row = mt * 16 + (l >> 4) * 4 + i;
        int col = w * 64 + nt * 16 + (l & 15);
        sOut[row * 264 + col] = f2b(ELUF(acc[mt][nt][i]));
      }
  __syncthreads();
#pragma unroll
  for (int j = 0; j < 4; ++j) {
    int u = t + j * 256;
    int r = u >> 5, ks = u & 31;
    *(uint4*)(eout + (e0 + r) * 256 + ks * 8) = *(const uint4*)&sOut[r * 264 + ks * 8];
  }
}

// ---------- fused node layer: out = elu(xin@W_self + sum_k alpha_k * eproj[e_k])
// softmax over k of lrelu(xin.a_s + sed[e_k]); 32 nodes/block, 256 threads.
__global__ __launch_bounds__(256, 2) void node_out(
    const ushort_t* __restrict__ xb,     // bf16 [N][256] (xin)
    const int* __restrict__ n2e,         // [N][8]
    const ushort_t* __restrict__ eproj,  // bf16 [E][256]
    const float* __restrict__ sed,       // f32 [E][4]
    const float* __restrict__ a_s,       // f32 [4][256]
    const ushort_t* __restrict__ WtS,    // bf16 [256][256]
    float* __restrict__ outp,            // f32, row stride 512
    ushort_t* __restrict__ xout) {       // bf16 [N][256] or nullptr
  __shared__ __align__(16) char smem[33280 + 1024 + 4096 + 4096];
  ushort_t (*sX)[32]   = (ushort_t(*)[32])smem;            // [32][32]   (K-loop)
  ushort_t (*sBs)[32]  = (ushort_t(*)[32])(smem + 2048);   // [256][32]  (K-loop)
  ushort_t (*sAs)[256] = (ushort_t(*)[256])(smem + 18432); // [4][256]   (K-loop)
  float* sOutF         = (float*)smem;                      // overlay [32][260] f32 (33280B)
  int*   sIdx          = (int*)(smem + 33280);              // [256]
  float* sSe           = (float*)(smem + 34304);            // [256][4]
  float* sAln          = (float*)(smem + 38400);            // [32][4][8]
  int t = threadIdx.x, w = t >> 6, l = t & 63;
  long n0 = (long)blockIdx.x * 32;

  {  // prologue: edge ids + score gather
    int e = n2e[n0 * 8 + t];
    sIdx[t] = e;
    *(float4*)&sSe[t * 4] = *(const float4*)(sed + (long)e * 4);
  }
  if (t < 128) {  // stage a_s as bf16
    int row = t >> 5, dof = (t & 31) * 8;
    float f[8]; ld8(a_s + row * 256 + dof, f);
    *(uint4*)&sAs[row][dof] = enc8(f);
  }

  f32x4 zero = {0.f, 0.f, 0.f, 0.f};
  f32x4 acc[2][4];
#pragma unroll
  for (int mt = 0; mt < 2; ++mt)
#pragma unroll
    for (int nt = 0; nt < 4; ++nt) acc[mt][nt] = zero;
  float ssp = 0.f;
  int sn = t >> 3, shalf = (t & 1) * 16, sh = (t >> 1) & 3;

  for (int kc = 0; kc < 8; ++kc) {
    __syncthreads();
    if (w == 0) {
#pragma unroll
      for (int j = 0; j < 2; ++j) {
        int u = j * 64 + l;
        int r = u >> 2, ks = u & 3;
        async16((char*)sX + j * 1024, xb + (n0 + r) * 256 + kc * 32 + ks * 8);
      }
    }
#pragma unroll
    for (int j = 0; j < 4; ++j) {
      int u = (w * 4 + j) * 64 + l;
      int n = u >> 2, ks = u & 3;
      async16((char*)sBs + (w * 4 + j) * 1024, WtS + (long)n * 256 + kc * 32 + ks * 8);
    }
    __syncthreads();
    bf16x8 ax[2], bs[4];
#pragma unroll
    for (int mt = 0; mt < 2; ++mt)
      ax[mt] = *(const bf16x8*)&sX[mt * 16 + (l & 15)][(l >> 4) * 8];
#pragma unroll
    for (int nt = 0; nt < 4; ++nt)
      bs[nt] = *(const bf16x8*)&sBs[w * 64 + nt * 16 + (l & 15)][(l >> 4) * 8];
#pragma unroll
    for (int mt = 0; mt < 2; ++mt)
#pragma unroll
      for (int nt = 0; nt < 4; ++nt)
        acc[mt][nt] = __builtin_amdgcn_mfma_f32_16x16x32_bf16(ax[mt], bs[nt], acc[mt][nt], 0, 0, 0);
    {  // fused ss partial: thread (node sn, head sh, half) does 16 dims
      float xv[16], av[16];
      dec8(*(const uint4*)&sX[sn][shalf], xv);
      dec8(*(const uint4*)&sX[sn][shalf + 8], xv + 8);
      dec8(*(const uint4*)&sAs[sh][kc * 32 + shalf], av);
      dec8(*(const uint4*)&sAs[sh][kc * 32 + shalf + 8], av + 8);
#pragma unroll
      for (int d = 0; d < 16; ++d) ssp += xv[d] * av[d];
    }
  }
  __syncthreads();
  // self-projection acc -> sOutF (pre-ELU, f32)
#pragma unroll
  for (int mt = 0; mt < 2; ++mt)
#pragma unroll
    for (int nt = 0; nt < 4; ++nt)
#pragma unroll
      for (int i = 0; i < 4; ++i) {
        int row = mt * 16 + (l >> 4) * 4 + i;
        int col = w * 64 + nt * 16 + (l & 15);
        sOutF[row * 260 + col] = acc[mt][nt][i];
      }
  // combine ss halves + per-(node,head) softmax over K=8
  float ssv = ssp + __shfl_xor(ssp, 1, 64);
  if (!(t & 1)) {
    float sv[8], mx = -1e30f;
#pragma unroll
    for (int k = 0; k < 8; ++k) {
      float s = ssv + sSe[(sn * 8 + k) * 4 + sh];
      s = s > 0.f ? s : 0.2f * s;
      sv[k] = s; mx = fmaxf(mx, s);
    }
    float sum = 0.f;
#pragma unroll
    for (int k = 0; k < 8; ++k) { sv[k] = __expf(sv[k] - mx); sum += sv[k]; }
    float inv = 1.f / sum;
#pragma unroll
    for (int k = 0; k < 8; ++k) sAln[(sn * 4 + sh) * 8 + k] = sv[k] * inv;
  }
  __syncthreads();

  // gather-weighted combine: 8 threads per node, 32 dims each
  int nT = t >> 3, sT = t & 7, hh = sT >> 1, dof = sT * 32;
  float wts[8];
#pragma unroll
  for (int k = 0; k < 8; ++k) wts[k] = sAln[(nT * 4 + hh) * 8 + k];
  int eidx[8];
#pragma unroll
  for (int k = 0; k < 8; ++k) eidx[k] = sIdx[nT * 8 + k];
  float o[32];
#pragma unroll
  for (int j = 0; j < 8; ++j) {
    float4 sv = *(const float4*)&sOutF[nT * 260 + dof + j * 4];
    o[j * 4 + 0] = sv.x; o[j * 4 + 1] = sv.y; o[j * 4 + 2] = sv.z; o[j * 4 + 3] = sv.w;
  }
#pragma unroll
  for (int k = 0; k < 8; ++k) {
    const ushort_t* pr = eproj + (long)eidx[k] * 256 + dof;
    float v[32];
    dec8(*(const uint4*)(pr),      v);
    dec8(*(const uint4*)(pr + 8),  v + 8);
    dec8(*(const uint4*)(pr + 16), v + 16);
    dec8(*(const uint4*)(pr + 24), v + 24);
    float wk = wts[k];
#pragma unroll
    for (int d = 0; d < 32; ++d) o[d] += wk * v[d];
  }
  long row = n0 + nT;
  float res[32];
#pragma unroll
  for (int d = 0; d < 32; ++d) res[d] = ELUF(o[d]);
  float* po = outp + row * 512 + dof;
#pragma unroll
  for (int j = 0; j < 8; ++j) {
    float4 q;
    q.x = res[j * 4 + 0]; q.y = res[j * 4 + 1]; q.z = res[j * 4 + 2]; q.w = res[j * 4 + 3];
    *(float4*)(po + j * 4) = q;
  }
  if (xout) {
#pragma unroll
    for (int j = 0; j < 4; ++j)
      *(uint4*)(xout + row * 256 + dof + j * 8) = enc8(res + j * 8);
  }
}

extern "C" void kernel_launch(void* const* d_in, const int* in_sizes, int n_in,
                              void* d_out, int out_size, void* d_ws, size_t ws_size,
                              hipStream_t stream) {
  (void)in_sizes; (void)n_in; (void)out_size; (void)ws_size;
  const float* feats  = (const float*)d_in[0];
  const float* eemb   = (const float*)d_in[1];
  const int*   adj    = (const int*)d_in[2];
  const int*   n2e    = (const int*)d_in[3];
  const float* Wp0    = (const float*)d_in[4];
  const float* Wp1    = (const float*)d_in[5];
  const float* Wep    = (const float*)d_in[6];
  const float* a_e    = (const float*)d_in[7];
  const float* a_n    = (const float*)d_in[8];
  const float* W_e    = (const float*)d_in[9];
  const float* a_s    = (const float*)d_in[10];
  const float* a_edge = (const float*)d_in[11];
  const float* W_self = (const float*)d_in[12];
  const float* W_nb   = (const float*)d_in[13];
  float* out = (float*)d_out;

  // workspace carve (~490 MB)
  char* w = (char*)d_ws;
  ushort_t* dummy_bf = (ushort_t*)w; w += (size_t)N_NODES * 256 * 2;
  ushort_t* base_bf  = (ushort_t*)w; w += (size_t)N_NODES * 256 * 2;
  ushort_t* edgesA   = (ushort_t*)w; w += (size_t)N_EDGES * 256 * 2;
  ushort_t* edgesB   = (ushort_t*)w; w += (size_t)N_EDGES * 256 * 2;
  ushort_t* eproj    = (ushort_t*)w; w += (size_t)N_EDGES * 256 * 2;
  float*    sed      = (float*)w;    w += (size_t)N_EDGES * 4 * 4;
  ushort_t* xl1      = (ushort_t*)w; w += (size_t)N_NODES * 256 * 2;
  ushort_t* WtP0     = (ushort_t*)w; w += 256 * 256 * 2;
  ushort_t* WtP1     = (ushort_t*)w; w += 256 * 256 * 2;
  ushort_t* WtEp     = (ushort_t*)w; w += 2 * 256 * 64 * 2;
  ushort_t* WtE      = (ushort_t*)w; w += 16 * 16384 * 2;
  ushort_t* WtS      = (ushort_t*)w; w += 16 * 16384 * 2;
  ushort_t* WtN      = (ushort_t*)w; w += 16 * 16384 * 2;

  // weight pre-transpose to bf16 Wt[n][k]
  wt_kernel<<<dim3(256, 1), 256, 0, stream>>>(Wp0, WtP0, 256, 256);
  wt_kernel<<<dim3(256, 1), 256, 0, stream>>>(Wp1, WtP1, 256, 256);
  wt_kernel<<<dim3(64, 2), 256, 0, stream>>>(Wep, WtEp, 64, 256);
  wt_kernel<<<dim3(64, 16), 256, 0, stream>>>(W_e, WtE, 256, 64);
  wt_kernel<<<dim3(64, 16), 256, 0, stream>>>(W_self, WtS, 256, 64);
  wt_kernel<<<dim3(64, 16), 256, 0, stream>>>(W_nb, WtN, 256, 64);

  // prep GEMMs
  gemm_mfma<<<N_NODES / 64, 256, 0, stream>>>(feats, WtP0, dummy_bf, 256);
  gemm_mfma<<<N_NODES / 64, 256, 0, stream>>>(feats, WtP1, base_bf, 256);

  for (int mp = 0; mp < 2; ++mp) {
    const int* adj_mp = adj + (size_t)mp * N_EDGES * 2;
    const int* n2e_mp = n2e + (size_t)mp * N_NODES * 8;
    size_t ao0 = (size_t)(mp * 2 + 0) * 1024, ao1 = (size_t)(mp * 2 + 1) * 1024;
    size_t wo0 = (size_t)(mp * 2 + 0) * 65536, wo1 = (size_t)(mp * 2 + 1) * 65536;

    gemm_mfma<<<N_EDGES / 64, 256, 0, stream>>>(
        eemb + (size_t)mp * N_EDGES * 64, WtEp + (size_t)mp * 16384, edgesA, 64);

    // L = 0
    gemm_eproj<<<N_EDGES / 64, 256, 0, stream>>>(edgesA, WtN + wo0, a_edge + ao0, eproj, sed);
    edge_kernel<<<N_EDGES / 32, 256, 0, stream>>>(base_bf, edgesA, edgesB, adj_mp,
                                                  a_n + ao0, a_e + ao0, WtE + wo0);
    node_out<<<N_NODES / 32, 256, 0, stream>>>(dummy_bf, n2e_mp, eproj, sed,
                                               a_s + ao0, WtS + wo0,
                                               out + (size_t)mp * N_NODES * 512, xl1);
    // L = 1 (last-layer edge aggregator output is dead -> only eproj of edgesB needed)
    gemm_eproj<<<N_EDGES / 64, 256, 0, stream>>>(edgesB, WtN + wo1, a_edge + ao1, eproj, sed);
    node_out<<<N_NODES / 32, 256, 0, stream>>>(xl1, n2e_mp, eproj, sed,
                                               a_s + ao1, WtS + wo1,
                                               out + (size_t)mp * N_NODES * 512 + 256,
                                               (ushort_t*)nullptr);
  }
}

// Round 2
// 1583.814 us; speedup vs baseline: 1.2187x; 1.0032x over previous
//
#include <hip/hip_runtime.h>

typedef unsigned short ushort_t;
typedef unsigned int uint_t;

#define N_NODES 65536
#define N_EDGES 262144

typedef __attribute__((ext_vector_type(8))) short bf16x8;
typedef __attribute__((ext_vector_type(4))) float f32x4;

// ---------- bf16 helpers ----------
__device__ __forceinline__ ushort_t f2b(float x) {
  uint_t u = __float_as_uint(x);
  u += 0x7fffu + ((u >> 16) & 1u);  // RNE
  return (ushort_t)(u >> 16);
}
__device__ __forceinline__ void dec8(uint4 v, float* f) {
  f[0] = __uint_as_float(v.x << 16); f[1] = __uint_as_float(v.x & 0xffff0000u);
  f[2] = __uint_as_float(v.y << 16); f[3] = __uint_as_float(v.y & 0xffff0000u);
  f[4] = __uint_as_float(v.z << 16); f[5] = __uint_as_float(v.z & 0xffff0000u);
  f[6] = __uint_as_float(v.w << 16); f[7] = __uint_as_float(v.w & 0xffff0000u);
}
__device__ __forceinline__ void dec4(uint2 v, float* f) {
  f[0] = __uint_as_float(v.x << 16); f[1] = __uint_as_float(v.x & 0xffff0000u);
  f[2] = __uint_as_float(v.y << 16); f[3] = __uint_as_float(v.y & 0xffff0000u);
}
__device__ __forceinline__ uint4 enc8(const float* f) {
  uint4 v;
  v.x = (uint_t)f2b(f[0]) | ((uint_t)f2b(f[1]) << 16);
  v.y = (uint_t)f2b(f[2]) | ((uint_t)f2b(f[3]) << 16);
  v.z = (uint_t)f2b(f[4]) | ((uint_t)f2b(f[5]) << 16);
  v.w = (uint_t)f2b(f[6]) | ((uint_t)f2b(f[7]) << 16);
  return v;
}
__device__ __forceinline__ uint2 enc4(const float* f) {
  uint2 v;
  v.x = (uint_t)f2b(f[0]) | ((uint_t)f2b(f[1]) << 16);
  v.y = (uint_t)f2b(f[2]) | ((uint_t)f2b(f[3]) << 16);
  return v;
}
__device__ __forceinline__ void ld8(const float* p, float* f) {
  float4 v0 = *(const float4*)p;
  float4 v1 = *(const float4*)(p + 4);
  f[0]=v0.x; f[1]=v0.y; f[2]=v0.z; f[3]=v0.w;
  f[4]=v1.x; f[5]=v1.y; f[6]=v1.z; f[7]=v1.w;
}

#define ELUF(v) ((v) > 0.f ? (v) : __expf(v) - 1.f)

// async global->LDS, 16B per lane; lds base must be wave-uniform (lane deposits at base+lane*16)
__device__ __forceinline__ void async16(void* lds, const void* g) {
  __builtin_amdgcn_global_load_lds(
      (const __attribute__((address_space(1))) void*)g,
      (__attribute__((address_space(3))) void*)lds, 16, 0, 0);
}

// ---------- weight transpose+cvt: dst[m][n*K+k] = bf16(src[m][k*N+n]) ----------
__global__ void wt_kernel(const float* __restrict__ src, ushort_t* __restrict__ dst,
                          int K, int N) {
  long m = blockIdx.y;
  long base = m * (long)K * N;
  int tid = blockIdx.x * 256 + threadIdx.x;
  if (tid >= K * N) return;
  int k = tid % K, n = tid / K;
  dst[base + (long)n * K + k] = f2b(src[base + (long)k * N + n]);
}

// ---------- MFMA GEMM: outb[rows][256] = bf16( A_f32[rows][K] @ Wt^T ), Wt bf16 [256][K] ----------
__global__ __launch_bounds__(256, 2) void gemm_mfma(
    const float* __restrict__ A, const ushort_t* __restrict__ Wt,
    ushort_t* __restrict__ outb, int K) {
  __shared__ __align__(16) char smem[4096 + 16384];
  ushort_t (*sA)[32] = (ushort_t(*)[32])smem;           // [64][32] bf16
  ushort_t (*sB)[32] = (ushort_t(*)[32])(smem + 4096);  // [256][32] bf16
  int t = threadIdx.x, w = t >> 6, l = t & 63;
  long r0 = (long)blockIdx.x * 64;
  f32x4 zero = {0.f, 0.f, 0.f, 0.f};
  f32x4 acc[4][4];
#pragma unroll
  for (int mt = 0; mt < 4; ++mt)
#pragma unroll
    for (int nt = 0; nt < 4; ++nt) acc[mt][nt] = zero;

  for (int kc = 0; kc < K / 32; ++kc) {
    __syncthreads();
    {  // stage A (f32 -> bf16)
      int r = t >> 2, ks8 = (t & 3) * 8;
      float f[8]; ld8(A + (r0 + r) * (long)K + kc * 32 + ks8, f);
      *(uint4*)&sA[r][ks8] = enc8(f);
    }
#pragma unroll
    for (int j = 0; j < 4; ++j) {  // stage B async
      int u = (w * 4 + j) * 64 + l;
      int n = u >> 2, ks = u & 3;
      async16((char*)sB + (w * 4 + j) * 1024, Wt + (long)n * K + kc * 32 + ks * 8);
    }
    __syncthreads();
    bf16x8 af[4], bf[4];
#pragma unroll
    for (int mt = 0; mt < 4; ++mt)
      af[mt] = *(const bf16x8*)&sA[mt * 16 + (l & 15)][(l >> 4) * 8];
#pragma unroll
    for (int nt = 0; nt < 4; ++nt)
      bf[nt] = *(const bf16x8*)&sB[w * 64 + nt * 16 + (l & 15)][(l >> 4) * 8];
#pragma unroll
    for (int mt = 0; mt < 4; ++mt)
#pragma unroll
      for (int nt = 0; nt < 4; ++nt)
        acc[mt][nt] = __builtin_amdgcn_mfma_f32_16x16x32_bf16(af[mt], bf[nt], acc[mt][nt], 0, 0, 0);
  }
#pragma unroll
  for (int mt = 0; mt < 4; ++mt)
#pragma unroll
    for (int nt = 0; nt < 4; ++nt)
#pragma unroll
      for (int i = 0; i < 4; ++i) {
        long row = r0 + mt * 16 + (l >> 4) * 4 + i;
        int col = w * 64 + nt * 16 + (l & 15);
        outb[row * 256 + col] = f2b(acc[mt][nt][i]);
      }
}

// ---------- eproj GEMM: outb[rows][256] = bf16(A @ Wt^T), + fused scores[rows][4] = A . a_vec^T
__global__ __launch_bounds__(256, 2) void gemm_eproj(
    const ushort_t* __restrict__ A, const ushort_t* __restrict__ Wt,
    const float* __restrict__ a_vec,  // f32 [4][256]
    ushort_t* __restrict__ outb, float* __restrict__ sco) {
  __shared__ __align__(16) char smem[4096 + 16384 + 8192];
  ushort_t (*sA)[32]   = (ushort_t(*)[32])smem;            // [64][32]
  ushort_t (*sB)[32]   = (ushort_t(*)[32])(smem + 4096);   // [256][32]
  ushort_t (*sAe)[256] = (ushort_t(*)[256])(smem + 20480); // [16][256], rows 4..15 zero
  int t = threadIdx.x, w = t >> 6, l = t & 63;
  long r0 = (long)blockIdx.x * 64;

  {  // stage a_vec^T as B-layout tile (16 cols, cols>=4 zero)
    int row = t >> 4, seg = (t & 15) * 16;
    float f[16];
    if (row < 4) {
      ld8(a_vec + row * 256 + seg, f);
      ld8(a_vec + row * 256 + seg + 8, f + 8);
    } else {
#pragma unroll
      for (int i = 0; i < 16; ++i) f[i] = 0.f;
    }
    *(uint4*)&sAe[row][seg] = enc8(f);
    *(uint4*)&sAe[row][seg + 8] = enc8(f + 8);
  }

  f32x4 zero = {0.f, 0.f, 0.f, 0.f};
  f32x4 acc[4][4];
  f32x4 accs[4];
#pragma unroll
  for (int mt = 0; mt < 4; ++mt) {
    accs[mt] = zero;
#pragma unroll
    for (int nt = 0; nt < 4; ++nt) acc[mt][nt] = zero;
  }

  for (int kc = 0; kc < 8; ++kc) {
    __syncthreads();
    async16((char*)sA + w * 1024, A + (r0 + (t >> 2)) * 256 + kc * 32 + (t & 3) * 8);
#pragma unroll
    for (int j = 0; j < 4; ++j) {  // stage B
      int u = (w * 4 + j) * 64 + l;
      int n = u >> 2, ks = u & 3;
      async16((char*)sB + (w * 4 + j) * 1024, Wt + (long)n * 256 + kc * 32 + ks * 8);
    }
    __syncthreads();
    bf16x8 af[4], bf[4];
#pragma unroll
    for (int mt = 0; mt < 4; ++mt)
      af[mt] = *(const bf16x8*)&sA[mt * 16 + (l & 15)][(l >> 4) * 8];
#pragma unroll
    for (int nt = 0; nt < 4; ++nt)
      bf[nt] = *(const bf16x8*)&sB[w * 64 + nt * 16 + (l & 15)][(l >> 4) * 8];
#pragma unroll
    for (int mt = 0; mt < 4; ++mt)
#pragma unroll
      for (int nt = 0; nt < 4; ++nt)
        acc[mt][nt] = __builtin_amdgcn_mfma_f32_16x16x32_bf16(af[mt], bf[nt], acc[mt][nt], 0, 0, 0);
    if (w == 0) {  // fused scores: A @ a_vec^T
      bf16x8 bs = *(const bf16x8*)&sAe[l & 15][kc * 32 + (l >> 4) * 8];
#pragma unroll
      for (int mt = 0; mt < 4; ++mt)
        accs[mt] = __builtin_amdgcn_mfma_f32_16x16x32_bf16(af[mt], bs, accs[mt], 0, 0, 0);
    }
  }
#pragma unroll
  for (int mt = 0; mt < 4; ++mt)
#pragma unroll
    for (int nt = 0; nt < 4; ++nt)
#pragma unroll
      for (int i = 0; i < 4; ++i) {
        long row = r0 + mt * 16 + (l >> 4) * 4 + i;
        int col = w * 64 + nt * 16 + (l & 15);
        outb[row * 256 + col] = f2b(acc[mt][nt][i]);
      }
  if (w == 0 && (l & 15) < 4) {
#pragma unroll
    for (int mt = 0; mt < 4; ++mt)
#pragma unroll
      for (int i = 0; i < 4; ++i) {
        long row = r0 + mt * 16 + (l >> 4) * 4 + i;
        sco[row * 4 + (l & 15)] = accs[mt][i];
      }
  }
}

// ---------- fused edge-combine + L1 eproj GEMM ----------
// A-tile rows = edgesB[e] = elu(eprojE[e] + a0*xprojE[n0] + a1*xprojE[n1]) (head = k/64),
// consumed in-LDS by MFMA vs WtN(L1); emits eproj_L1 and sed_L1 = edgesB . a_edge(L1)^T.
__global__ __launch_bounds__(256, 2) void edge_combine(
    const int* __restrict__ ena,          // [E][2]
    const ushort_t* __restrict__ eprojE,  // bf16 [E][256]
    const ushort_t* __restrict__ xprojE,  // bf16 [N][256]
    const float* __restrict__ xan,        // f32 [N][4]
    const float* __restrict__ sea,        // f32 [E][4]
    const ushort_t* __restrict__ Wt,      // W_nb L1 bf16 [256][256]
    const float* __restrict__ a_edge,     // L1 f32 [4][256]
    ushort_t* __restrict__ outb,          // eproj_L1 bf16 [E][256]
    float* __restrict__ sed) {            // sed_L1 f32 [E][4]
  __shared__ __align__(16) char smem[4096 + 16384 + 8192 + 2048 + 512];
  ushort_t (*sY)[32]   = (ushort_t(*)[32])smem;            // [64][32] A tile
  ushort_t (*sB)[32]   = (ushort_t(*)[32])(smem + 4096);   // [256][32]
  ushort_t (*sAe)[256] = (ushort_t(*)[256])(smem + 20480); // [16][256], rows 4..15 zero
  float (*sAlp)[4][2]  = (float(*)[4][2])(smem + 28672);   // [64][4][2]
  int* sIdx            = (int*)(smem + 30720);             // [128]
  int t = threadIdx.x, w = t >> 6, l = t & 63;
  long e0 = (long)blockIdx.x * 64;

  {  // stage a_edge(L1)^T tile
    int row = t >> 4, seg = (t & 15) * 16;
    float f[16];
    if (row < 4) {
      ld8(a_edge + row * 256 + seg, f);
      ld8(a_edge + row * 256 + seg + 8, f + 8);
    } else {
#pragma unroll
      for (int i = 0; i < 16; ++i) f[i] = 0.f;
    }
    *(uint4*)&sAe[row][seg] = enc8(f);
    *(uint4*)&sAe[row][seg + 8] = enc8(f + 8);
  }
  if (t < 128) sIdx[t] = ena[e0 * 2 + t];
  __syncthreads();

  {  // per-(edge,head) 2-way softmax from precomputed scores
    int e = t >> 2, h = t & 3;
    int n0 = sIdx[2 * e], n1 = sIdx[2 * e + 1];
    float sE = sea[(e0 + e) * 4 + h];
    float s0 = xan[(long)n0 * 4 + h] + sE; s0 = s0 > 0.f ? s0 : 0.2f * s0;
    float s1 = xan[(long)n1 * 4 + h] + sE; s1 = s1 > 0.f ? s1 : 0.2f * s1;
    float mx = fmaxf(s0, s1);
    float g0 = __expf(s0 - mx), g1 = __expf(s1 - mx);
    float inv = 1.f / (g0 + g1);
    sAlp[e][h][0] = g0 * inv;
    sAlp[e][h][1] = g1 * inv;
  }

  int r = t >> 2, c0 = (t & 3) * 8;
  int n0r = sIdx[2 * r], n1r = sIdx[2 * r + 1];
  const ushort_t* pe = eprojE + (e0 + r) * 256 + c0;
  const ushort_t* p0 = xprojE + (long)n0r * 256 + c0;
  const ushort_t* p1 = xprojE + (long)n1r * 256 + c0;

  f32x4 zero = {0.f, 0.f, 0.f, 0.f};
  f32x4 acc[4][4];
  f32x4 accs[4];
#pragma unroll
  for (int mt = 0; mt < 4; ++mt) {
    accs[mt] = zero;
#pragma unroll
    for (int nt = 0; nt < 4; ++nt) acc[mt][nt] = zero;
  }

  for (int kc = 0; kc < 8; ++kc) {
    __syncthreads();  // publishes sAlp (iter 0) / guards sY reuse
#pragma unroll
    for (int j = 0; j < 4; ++j) {  // stage B (WtN L1)
      int u = (w * 4 + j) * 64 + l;
      int n = u >> 2, ks = u & 3;
      async16((char*)sB + (w * 4 + j) * 1024, Wt + (long)n * 256 + kc * 32 + ks * 8);
    }
    {  // build A tile for this k-chunk (head h = kc>>1)
      int h = kc >> 1;
      float a0 = sAlp[r][h][0], a1 = sAlp[r][h][1];
      float ep[8], x0[8], x1[8], y[8];
      dec8(*(const uint4*)(pe + kc * 32), ep);
      dec8(*(const uint4*)(p0 + kc * 32), x0);
      dec8(*(const uint4*)(p1 + kc * 32), x1);
#pragma unroll
      for (int d = 0; d < 8; ++d) {
        float v = ep[d] + a0 * x0[d] + a1 * x1[d];
        y[d] = ELUF(v);
      }
      *(uint4*)&sY[r][c0] = enc8(y);
    }
    __syncthreads();
    bf16x8 af[4], bf[4];
#pragma unroll
    for (int mt = 0; mt < 4; ++mt)
      af[mt] = *(const bf16x8*)&sY[mt * 16 + (l & 15)][(l >> 4) * 8];
#pragma unroll
    for (int nt = 0; nt < 4; ++nt)
      bf[nt] = *(const bf16x8*)&sB[w * 64 + nt * 16 + (l & 15)][(l >> 4) * 8];
#pragma unroll
    for (int mt = 0; mt < 4; ++mt)
#pragma unroll
      for (int nt = 0; nt < 4; ++nt)
        acc[mt][nt] = __builtin_amdgcn_mfma_f32_16x16x32_bf16(af[mt], bf[nt], acc[mt][nt], 0, 0, 0);
    if (w == 0) {  // fused sed_L1
      bf16x8 bs = *(const bf16x8*)&sAe[l & 15][kc * 32 + (l >> 4) * 8];
#pragma unroll
      for (int mt = 0; mt < 4; ++mt)
        accs[mt] = __builtin_amdgcn_mfma_f32_16x16x32_bf16(af[mt], bs, accs[mt], 0, 0, 0);
    }
  }
#pragma unroll
  for (int mt = 0; mt < 4; ++mt)
#pragma unroll
    for (int nt = 0; nt < 4; ++nt)
#pragma unroll
      for (int i = 0; i < 4; ++i) {
        long row = e0 + mt * 16 + (l >> 4) * 4 + i;
        int col = w * 64 + nt * 16 + (l & 15);
        outb[row * 256 + col] = f2b(acc[mt][nt][i]);
      }
  if (w == 0 && (l & 15) < 4) {
#pragma unroll
    for (int mt = 0; mt < 4; ++mt)
#pragma unroll
      for (int i = 0; i < 4; ++i) {
        long row = e0 + mt * 16 + (l >> 4) * 4 + i;
        sed[row * 4 + (l & 15)] = accs[mt][i];
      }
  }
}

// ---------- fused node layer: out = elu(xin@W_self + sum_k alpha_k * eproj[e_k]) ----------
__global__ __launch_bounds__(256, 2) void node_out(
    const ushort_t* __restrict__ xb,     // bf16 [N][256] (xin)
    const int* __restrict__ n2e,         // [N][8]
    const ushort_t* __restrict__ eproj,  // bf16 [E][256]
    const float* __restrict__ sed,       // f32 [E][4]
    const float* __restrict__ a_s,       // f32 [4][256]
    const ushort_t* __restrict__ WtS,    // bf16 [256][256]
    float* __restrict__ outp,            // f32, row stride 512
    ushort_t* __restrict__ xout) {       // bf16 [N][256] or nullptr
  __shared__ __align__(16) char smem[33280 + 1024 + 4096 + 4096];
  ushort_t (*sX)[32]   = (ushort_t(*)[32])smem;            // [32][32]   (K-loop)
  ushort_t (*sBs)[32]  = (ushort_t(*)[32])(smem + 2048);   // [256][32]  (K-loop)
  ushort_t (*sAs)[256] = (ushort_t(*)[256])(smem + 18432); // [4][256]   (K-loop)
  float* sOutF         = (float*)smem;                      // overlay [32][260] f32 (33280B)
  int*   sIdx          = (int*)(smem + 33280);              // [256]
  float* sSe           = (float*)(smem + 34304);            // [256][4]
  float* sAln          = (float*)(smem + 38400);            // [32][4][8]
  int t = threadIdx.x, w = t >> 6, l = t & 63;
  long n0 = (long)blockIdx.x * 32;

  {  // prologue: edge ids + score gather
    int e = n2e[n0 * 8 + t];
    sIdx[t] = e;
    *(float4*)&sSe[t * 4] = *(const float4*)(sed + (long)e * 4);
  }
  if (t < 128) {  // stage a_s as bf16
    int row = t >> 5, dof = (t & 31) * 8;
    float f[8]; ld8(a_s + row * 256 + dof, f);
    *(uint4*)&sAs[row][dof] = enc8(f);
  }

  f32x4 zero = {0.f, 0.f, 0.f, 0.f};
  f32x4 acc[2][4];
#pragma unroll
  for (int mt = 0; mt < 2; ++mt)
#pragma unroll
    for (int nt = 0; nt < 4; ++nt) acc[mt][nt] = zero;
  float ssp = 0.f;
  int sn = t >> 3, shalf = (t & 1) * 16, sh = (t >> 1) & 3;

  for (int kc = 0; kc < 8; ++kc) {
    __syncthreads();
    if (w == 0) {
#pragma unroll
      for (int j = 0; j < 2; ++j) {
        int u = j * 64 + l;
        int r = u >> 2, ks = u & 3;
        async16((char*)sX + j * 1024, xb + (n0 + r) * 256 + kc * 32 + ks * 8);
      }
    }
#pragma unroll
    for (int j = 0; j < 4; ++j) {
      int u = (w * 4 + j) * 64 + l;
      int n = u >> 2, ks = u & 3;
      async16((char*)sBs + (w * 4 + j) * 1024, WtS + (long)n * 256 + kc * 32 + ks * 8);
    }
    __syncthreads();
    bf16x8 ax[2], bs[4];
#pragma unroll
    for (int mt = 0; mt < 2; ++mt)
      ax[mt] = *(const bf16x8*)&sX[mt * 16 + (l & 15)][(l >> 4) * 8];
#pragma unroll
    for (int nt = 0; nt < 4; ++nt)
      bs[nt] = *(const bf16x8*)&sBs[w * 64 + nt * 16 + (l & 15)][(l >> 4) * 8];
#pragma unroll
    for (int mt = 0; mt < 2; ++mt)
#pragma unroll
      for (int nt = 0; nt < 4; ++nt)
        acc[mt][nt] = __builtin_amdgcn_mfma_f32_16x16x32_bf16(ax[mt], bs[nt], acc[mt][nt], 0, 0, 0);
    {  // fused ss partial: thread (node sn, head sh, half) does 16 dims
      float xv[16], av[16];
      dec8(*(const uint4*)&sX[sn][shalf], xv);
      dec8(*(const uint4*)&sX[sn][shalf + 8], xv + 8);
      dec8(*(const uint4*)&sAs[sh][kc * 32 + shalf], av);
      dec8(*(const uint4*)&sAs[sh][kc * 32 + shalf + 8], av + 8);
#pragma unroll
      for (int d = 0; d < 16; ++d) ssp += xv[d] * av[d];
    }
  }
  __syncthreads();
#pragma unroll
  for (int mt = 0; mt < 2; ++mt)
#pragma unroll
    for (int nt = 0; nt < 4; ++nt)
#pragma unroll
      for (int i = 0; i < 4; ++i) {
        int row = mt * 16 + (l >> 4) * 4 + i;
        int col = w * 64 + nt * 16 + (l & 15);
        sOutF[row * 260 + col] = acc[mt][nt][i];
      }
  float ssv = ssp + __shfl_xor(ssp, 1, 64);
  if (!(t & 1)) {
    float sv[8], mx = -1e30f;
#pragma unroll
    for (int k = 0; k < 8; ++k) {
      float s = ssv + sSe[(sn * 8 + k) * 4 + sh];
      s = s > 0.f ? s : 0.2f * s;
      sv[k] = s; mx = fmaxf(mx, s);
    }
    float sum = 0.f;
#pragma unroll
    for (int k = 0; k < 8; ++k) { sv[k] = __expf(sv[k] - mx); sum += sv[k]; }
    float inv = 1.f / sum;
#pragma unroll
    for (int k = 0; k < 8; ++k) sAln[(sn * 4 + sh) * 8 + k] = sv[k] * inv;
  }
  __syncthreads();

  int nT = t >> 3, sT = t & 7, hh = sT >> 1, dof = sT * 32;
  float wts[8];
#pragma unroll
  for (int k = 0; k < 8; ++k) wts[k] = sAln[(nT * 4 + hh) * 8 + k];
  int eidx[8];
#pragma unroll
  for (int k = 0; k < 8; ++k) eidx[k] = sIdx[nT * 8 + k];
  float o[32];
#pragma unroll
  for (int j = 0; j < 8; ++j) {
    float4 sv = *(const float4*)&sOutF[nT * 260 + dof + j * 4];
    o[j * 4 + 0] = sv.x; o[j * 4 + 1] = sv.y; o[j * 4 + 2] = sv.z; o[j * 4 + 3] = sv.w;
  }
#pragma unroll
  for (int k = 0; k < 8; ++k) {
    const ushort_t* pr = eproj + (long)eidx[k] * 256 + dof;
    float v[32];
    dec8(*(const uint4*)(pr),      v);
    dec8(*(const uint4*)(pr + 8),  v + 8);
    dec8(*(const uint4*)(pr + 16), v + 16);
    dec8(*(const uint4*)(pr + 24), v + 24);
    float wk = wts[k];
#pragma unroll
    for (int d = 0; d < 32; ++d) o[d] += wk * v[d];
  }
  long row = n0 + nT;
  float res[32];
#pragma unroll
  for (int d = 0; d < 32; ++d) res[d] = ELUF(o[d]);
  float* po = outp + row * 512 + dof;
#pragma unroll
  for (int j = 0; j < 8; ++j) {
    float4 q;
    q.x = res[j * 4 + 0]; q.y = res[j * 4 + 1]; q.z = res[j * 4 + 2]; q.w = res[j * 4 + 3];
    *(float4*)(po + j * 4) = q;
  }
  if (xout) {
#pragma unroll
    for (int j = 0; j < 4; ++j)
      *(uint4*)(xout + row * 256 + dof + j * 8) = enc8(res + j * 8);
  }
}

extern "C" void kernel_launch(void* const* d_in, const int* in_sizes, int n_in,
                              void* d_out, int out_size, void* d_ws, size_t ws_size,
                              hipStream_t stream) {
  (void)in_sizes; (void)n_in; (void)out_size; (void)ws_size;
  const float* feats  = (const float*)d_in[0];
  const float* eemb   = (const float*)d_in[1];
  const int*   adj    = (const int*)d_in[2];
  const int*   n2e    = (const int*)d_in[3];
  const float* Wp0    = (const float*)d_in[4];
  const float* Wp1    = (const float*)d_in[5];
  const float* Wep    = (const float*)d_in[6];
  const float* a_e    = (const float*)d_in[7];
  const float* a_n    = (const float*)d_in[8];
  const float* W_e    = (const float*)d_in[9];
  const float* a_s    = (const float*)d_in[10];
  const float* a_edge = (const float*)d_in[11];
  const float* W_self = (const float*)d_in[12];
  const float* W_nb   = (const float*)d_in[13];
  float* out = (float*)d_out;

  // workspace carve (~495 MiB). Lifetimes per mp iteration:
  //   edgesA: w@1, r@2, r@4        -> buffer E_A
  //   eprojE: w@2, r@5(combine)    -> buffer E_B
  //   eproj0: w@4, r@6(node L0)    -> buffer E_C
  //   eprojL1: w@5, r@7(node L1)   -> aliases E_A (edgesA dead after step 4)
  //   xprojE: w@3, r@5 ; xl1: w@6, r@7 -> share buffer X
  char* w = (char*)d_ws;
  ushort_t* dummy_bf = (ushort_t*)w; w += (size_t)N_NODES * 256 * 2;
  ushort_t* base_bf  = (ushort_t*)w; w += (size_t)N_NODES * 256 * 2;
  ushort_t* bufEA    = (ushort_t*)w; w += (size_t)N_EDGES * 256 * 2;
  ushort_t* bufEB    = (ushort_t*)w; w += (size_t)N_EDGES * 256 * 2;
  ushort_t* bufEC    = (ushort_t*)w; w += (size_t)N_EDGES * 256 * 2;
  ushort_t* bufX     = (ushort_t*)w; w += (size_t)N_NODES * 256 * 2;
  float*    sea      = (float*)w;    w += (size_t)N_EDGES * 4 * 4;
  float*    sed0     = (float*)w;    w += (size_t)N_EDGES * 4 * 4;
  float*    sed1     = (float*)w;    w += (size_t)N_EDGES * 4 * 4;
  float*    xan      = (float*)w;    w += (size_t)N_NODES * 4 * 4;
  ushort_t* WtP0     = (ushort_t*)w; w += 256 * 256 * 2;
  ushort_t* WtP1     = (ushort_t*)w; w += 256 * 256 * 2;
  ushort_t* WtEp     = (ushort_t*)w; w += 2 * 256 * 64 * 2;
  ushort_t* WtE      = (ushort_t*)w; w += 16 * 16384 * 2;
  ushort_t* WtS      = (ushort_t*)w; w += 16 * 16384 * 2;
  ushort_t* WtN      = (ushort_t*)w; w += 16 * 16384 * 2;

  // weight pre-transpose to bf16 Wt[n][k]
  wt_kernel<<<dim3(256, 1), 256, 0, stream>>>(Wp0, WtP0, 256, 256);
  wt_kernel<<<dim3(256, 1), 256, 0, stream>>>(Wp1, WtP1, 256, 256);
  wt_kernel<<<dim3(64, 2), 256, 0, stream>>>(Wep, WtEp, 64, 256);
  wt_kernel<<<dim3(64, 16), 256, 0, stream>>>(W_e, WtE, 256, 64);
  wt_kernel<<<dim3(64, 16), 256, 0, stream>>>(W_self, WtS, 256, 64);
  wt_kernel<<<dim3(64, 16), 256, 0, stream>>>(W_nb, WtN, 256, 64);

  // prep GEMMs
  gemm_mfma<<<N_NODES / 64, 256, 0, stream>>>(feats, WtP0, dummy_bf, 256);
  gemm_mfma<<<N_NODES / 64, 256, 0, stream>>>(feats, WtP1, base_bf, 256);

  for (int mp = 0; mp < 2; ++mp) {
    const int* adj_mp = adj + (size_t)mp * N_EDGES * 2;
    const int* n2e_mp = n2e + (size_t)mp * N_NODES * 8;
    size_t ao0 = (size_t)(mp * 2 + 0) * 1024, ao1 = (size_t)(mp * 2 + 1) * 1024;
    size_t wo0 = (size_t)(mp * 2 + 0) * 65536, wo1 = (size_t)(mp * 2 + 1) * 65536;

    ushort_t* edgesA  = bufEA;
    ushort_t* eprojE  = bufEB;
    ushort_t* eproj0  = bufEC;
    ushort_t* eprojL1 = bufEA;  // alias (edgesA dead after step 4)
    ushort_t* xprojE  = bufX;
    ushort_t* xl1     = bufX;   // alias (xprojE dead after step 5)

    // 1. raw edge prep: edgesA = eemb @ W_eprep
    gemm_mfma<<<N_EDGES / 64, 256, 0, stream>>>(
        eemb + (size_t)mp * N_EDGES * 64, WtEp + (size_t)mp * 16384, edgesA, 64);
    // 2. eprojE = edgesA @ W_e(L0), sea = edgesA . a_e(L0)
    gemm_eproj<<<N_EDGES / 64, 256, 0, stream>>>(edgesA, WtE + wo0, a_e + ao0, eprojE, sea);
    // 3. xprojE = base @ W_e(L0), xan = base . a_n(L0)
    gemm_eproj<<<N_NODES / 64, 256, 0, stream>>>(base_bf, WtE + wo0, a_n + ao0, xprojE, xan);
    // 4. eproj0 = edgesA @ W_nb(L0), sed0 = edgesA . a_edge(L0)   [last read of edgesA]
    gemm_eproj<<<N_EDGES / 64, 256, 0, stream>>>(edgesA, WtN + wo0, a_edge + ao0, eproj0, sed0);
    // 5. fused edge-combine + L1 eproj (writes over edgesA buffer)
    edge_combine<<<N_EDGES / 64, 256, 0, stream>>>(adj_mp, eprojE, xprojE, xan, sea,
                                                   WtN + wo1, a_edge + ao1, eprojL1, sed1);
    // 6. node layer 0 (xin = dummy prep)
    node_out<<<N_NODES / 32, 256, 0, stream>>>(dummy_bf, n2e_mp, eproj0, sed0,
                                               a_s + ao0, WtS + wo0,
                                               out + (size_t)mp * N_NODES * 512, xl1);
    // 7. node layer 1
    node_out<<<N_NODES / 32, 256, 0, stream>>>(xl1, n2e_mp, eprojL1, sed1,
                                               a_s + ao1, WtS + wo1,
                                               out + (size_t)mp * N_NODES * 512 + 256,
                                               (ushort_t*)nullptr);
  }
}

// Round 3
// 1442.103 us; speedup vs baseline: 1.3384x; 1.0983x over previous
//
#include <hip/hip_runtime.h>

typedef unsigned short ushort_t;
typedef unsigned int uint_t;

#define N_NODES 65536
#define N_EDGES 262144

typedef __attribute__((ext_vector_type(8))) short bf16x8;
typedef __attribute__((ext_vector_type(4))) float f32x4;

// ---------- bf16 helpers ----------
__device__ __forceinline__ ushort_t f2b(float x) {
  uint_t u = __float_as_uint(x);
  u += 0x7fffu + ((u >> 16) & 1u);  // RNE
  return (ushort_t)(u >> 16);
}
__device__ __forceinline__ void dec8(uint4 v, float* f) {
  f[0] = __uint_as_float(v.x << 16); f[1] = __uint_as_float(v.x & 0xffff0000u);
  f[2] = __uint_as_float(v.y << 16); f[3] = __uint_as_float(v.y & 0xffff0000u);
  f[4] = __uint_as_float(v.z << 16); f[5] = __uint_as_float(v.z & 0xffff0000u);
  f[6] = __uint_as_float(v.w << 16); f[7] = __uint_as_float(v.w & 0xffff0000u);
}
__device__ __forceinline__ void dec4(uint2 v, float* f) {
  f[0] = __uint_as_float(v.x << 16); f[1] = __uint_as_float(v.x & 0xffff0000u);
  f[2] = __uint_as_float(v.y << 16); f[3] = __uint_as_float(v.y & 0xffff0000u);
}
__device__ __forceinline__ uint4 enc8(const float* f) {
  uint4 v;
  v.x = (uint_t)f2b(f[0]) | ((uint_t)f2b(f[1]) << 16);
  v.y = (uint_t)f2b(f[2]) | ((uint_t)f2b(f[3]) << 16);
  v.z = (uint_t)f2b(f[4]) | ((uint_t)f2b(f[5]) << 16);
  v.w = (uint_t)f2b(f[6]) | ((uint_t)f2b(f[7]) << 16);
  return v;
}
__device__ __forceinline__ uint2 enc4(const float* f) {
  uint2 v;
  v.x = (uint_t)f2b(f[0]) | ((uint_t)f2b(f[1]) << 16);
  v.y = (uint_t)f2b(f[2]) | ((uint_t)f2b(f[3]) << 16);
  return v;
}
__device__ __forceinline__ void ld8(const float* p, float* f) {
  float4 v0 = *(const float4*)p;
  float4 v1 = *(const float4*)(p + 4);
  f[0]=v0.x; f[1]=v0.y; f[2]=v0.z; f[3]=v0.w;
  f[4]=v1.x; f[5]=v1.y; f[6]=v1.z; f[7]=v1.w;
}

#define ELUF(v) ((v) > 0.f ? (v) : __expf(v) - 1.f)

// async global->LDS, 16B per lane; lds base must be wave-uniform (lane deposits at base+lane*16)
__device__ __forceinline__ void async16(void* lds, const void* g) {
  __builtin_amdgcn_global_load_lds(
      (const __attribute__((address_space(1))) void*)g,
      (__attribute__((address_space(3))) void*)lds, 16, 0, 0);
}

// ---------- weight transpose+cvt: dst[m][n*K+k] = bf16(src[m][k*N+n]) ----------
__global__ void wt_kernel(const float* __restrict__ src, ushort_t* __restrict__ dst,
                          int K, int N) {
  long m = blockIdx.y;
  long base = m * (long)K * N;
  int tid = blockIdx.x * 256 + threadIdx.x;
  if (tid >= K * N) return;
  int k = tid % K, n = tid / K;
  dst[base + (long)n * K + k] = f2b(src[base + (long)k * N + n]);
}

// ---------- dual MFMA GEMM: out{0,1}[rows][256] = bf16( A_f32[rows][256] @ Wt{0,1}^T ) ----------
__global__ __launch_bounds__(256, 2) void gemm_mfma2(
    const float* __restrict__ A, const ushort_t* __restrict__ Wt0,
    const ushort_t* __restrict__ Wt1, ushort_t* __restrict__ out0,
    ushort_t* __restrict__ out1) {
  __shared__ __align__(16) char smem[4096 + 16384 + 16384];
  ushort_t (*sA)[32]  = (ushort_t(*)[32])smem;             // [64][32]
  ushort_t (*sB0)[32] = (ushort_t(*)[32])(smem + 4096);    // [256][32]
  ushort_t (*sB1)[32] = (ushort_t(*)[32])(smem + 20480);   // [256][32]
  int t = threadIdx.x, w = t >> 6, l = t & 63;
  long r0 = (long)blockIdx.x * 64;
  f32x4 zero = {0.f, 0.f, 0.f, 0.f};
  f32x4 acc0[4][4], acc1[4][4];
#pragma unroll
  for (int mt = 0; mt < 4; ++mt)
#pragma unroll
    for (int nt = 0; nt < 4; ++nt) { acc0[mt][nt] = zero; acc1[mt][nt] = zero; }

  for (int kc = 0; kc < 8; ++kc) {
    __syncthreads();
    {  // stage A (f32 -> bf16)
      int r = t >> 2, ks8 = (t & 3) * 8;
      float f[8]; ld8(A + (r0 + r) * 256 + kc * 32 + ks8, f);
      *(uint4*)&sA[r][ks8] = enc8(f);
    }
#pragma unroll
    for (int j = 0; j < 4; ++j) {
      int u = (w * 4 + j) * 64 + l;
      int n = u >> 2, ks = u & 3;
      async16((char*)sB0 + (w * 4 + j) * 1024, Wt0 + (long)n * 256 + kc * 32 + ks * 8);
      async16((char*)sB1 + (w * 4 + j) * 1024, Wt1 + (long)n * 256 + kc * 32 + ks * 8);
    }
    __syncthreads();
    bf16x8 af[4];
#pragma unroll
    for (int mt = 0; mt < 4; ++mt)
      af[mt] = *(const bf16x8*)&sA[mt * 16 + (l & 15)][(l >> 4) * 8];
#pragma unroll
    for (int nt = 0; nt < 4; ++nt) {
      bf16x8 b0 = *(const bf16x8*)&sB0[w * 64 + nt * 16 + (l & 15)][(l >> 4) * 8];
      bf16x8 b1 = *(const bf16x8*)&sB1[w * 64 + nt * 16 + (l & 15)][(l >> 4) * 8];
#pragma unroll
      for (int mt = 0; mt < 4; ++mt) {
        acc0[mt][nt] = __builtin_amdgcn_mfma_f32_16x16x32_bf16(af[mt], b0, acc0[mt][nt], 0, 0, 0);
        acc1[mt][nt] = __builtin_amdgcn_mfma_f32_16x16x32_bf16(af[mt], b1, acc1[mt][nt], 0, 0, 0);
      }
    }
  }
#pragma unroll
  for (int mt = 0; mt < 4; ++mt)
#pragma unroll
    for (int nt = 0; nt < 4; ++nt)
#pragma unroll
      for (int i = 0; i < 4; ++i) {
        long row = r0 + mt * 16 + (l >> 4) * 4 + i;
        int col = w * 64 + nt * 16 + (l & 15);
        out0[row * 256 + col] = f2b(acc0[mt][nt][i]);
        out1[row * 256 + col] = f2b(acc1[mt][nt][i]);
      }
}

// ---------- eproj GEMM: outb[rows][256] = bf16(A @ Wt^T), + fused scores[rows][4] = A . a_vec^T
__global__ __launch_bounds__(256, 2) void gemm_eproj(
    const ushort_t* __restrict__ A, const ushort_t* __restrict__ Wt,
    const float* __restrict__ a_vec,  // f32 [4][256]
    ushort_t* __restrict__ outb, float* __restrict__ sco) {
  __shared__ __align__(16) char smem[4096 + 16384 + 8192];
  ushort_t (*sA)[32]   = (ushort_t(*)[32])smem;            // [64][32]
  ushort_t (*sB)[32]   = (ushort_t(*)[32])(smem + 4096);   // [256][32]
  ushort_t (*sAe)[256] = (ushort_t(*)[256])(smem + 20480); // [16][256], rows 4..15 zero
  int t = threadIdx.x, w = t >> 6, l = t & 63;
  long r0 = (long)blockIdx.x * 64;

  {  // stage a_vec^T as B-layout tile (16 cols, cols>=4 zero)
    int row = t >> 4, seg = (t & 15) * 16;
    float f[16];
    if (row < 4) {
      ld8(a_vec + row * 256 + seg, f);
      ld8(a_vec + row * 256 + seg + 8, f + 8);
    } else {
#pragma unroll
      for (int i = 0; i < 16; ++i) f[i] = 0.f;
    }
    *(uint4*)&sAe[row][seg] = enc8(f);
    *(uint4*)&sAe[row][seg + 8] = enc8(f + 8);
  }

  f32x4 zero = {0.f, 0.f, 0.f, 0.f};
  f32x4 acc[4][4];
  f32x4 accs[4];
#pragma unroll
  for (int mt = 0; mt < 4; ++mt) {
    accs[mt] = zero;
#pragma unroll
    for (int nt = 0; nt < 4; ++nt) acc[mt][nt] = zero;
  }

  for (int kc = 0; kc < 8; ++kc) {
    __syncthreads();
    async16((char*)sA + w * 1024, A + (r0 + (t >> 2)) * 256 + kc * 32 + (t & 3) * 8);
#pragma unroll
    for (int j = 0; j < 4; ++j) {  // stage B
      int u = (w * 4 + j) * 64 + l;
      int n = u >> 2, ks = u & 3;
      async16((char*)sB + (w * 4 + j) * 1024, Wt + (long)n * 256 + kc * 32 + ks * 8);
    }
    __syncthreads();
    bf16x8 af[4], bf[4];
#pragma unroll
    for (int mt = 0; mt < 4; ++mt)
      af[mt] = *(const bf16x8*)&sA[mt * 16 + (l & 15)][(l >> 4) * 8];
#pragma unroll
    for (int nt = 0; nt < 4; ++nt)
      bf[nt] = *(const bf16x8*)&sB[w * 64 + nt * 16 + (l & 15)][(l >> 4) * 8];
#pragma unroll
    for (int mt = 0; mt < 4; ++mt)
#pragma unroll
      for (int nt = 0; nt < 4; ++nt)
        acc[mt][nt] = __builtin_amdgcn_mfma_f32_16x16x32_bf16(af[mt], bf[nt], acc[mt][nt], 0, 0, 0);
    if (w == 0) {  // fused scores: A @ a_vec^T
      bf16x8 bs = *(const bf16x8*)&sAe[l & 15][kc * 32 + (l >> 4) * 8];
#pragma unroll
      for (int mt = 0; mt < 4; ++mt)
        accs[mt] = __builtin_amdgcn_mfma_f32_16x16x32_bf16(af[mt], bs, accs[mt], 0, 0, 0);
    }
  }
#pragma unroll
  for (int mt = 0; mt < 4; ++mt)
#pragma unroll
    for (int nt = 0; nt < 4; ++nt)
#pragma unroll
      for (int i = 0; i < 4; ++i) {
        long row = r0 + mt * 16 + (l >> 4) * 4 + i;
        int col = w * 64 + nt * 16 + (l & 15);
        outb[row * 256 + col] = f2b(acc[mt][nt][i]);
      }
  if (w == 0 && (l & 15) < 4) {
#pragma unroll
    for (int mt = 0; mt < 4; ++mt)
#pragma unroll
      for (int i = 0; i < 4; ++i) {
        long row = r0 + mt * 16 + (l >> 4) * 4 + i;
        sco[row * 4 + (l & 15)] = accs[mt][i];
      }
  }
}

// ---------- edge mega-kernel: whole edge pipeline on one resident 64x256 tile ----------
// Phase1: tile = eemb @ W_eprep -> LDS (swizzled).  PassA: tile @ W_nb(L0) -> eproj0 (+ sea/sed0).
// PassB: tile @ W_e(L0) -> overwrite LDS tile (= eprojE).  Phase3: per-kc combine
// elu(eprojE + a0*xprojE[n0] + a1*xprojE[n1]) @ W_nb(L1) -> eprojL1 (+ sed1).
__global__ __launch_bounds__(256, 2) void edge_mega(
    const float* __restrict__ eemb,       // [E][64] f32 (this mp)
    const ushort_t* __restrict__ WtEp,    // [256][64]
    const ushort_t* __restrict__ WtN0,    // [256][256] W_nb L0
    const ushort_t* __restrict__ WtE0,    // [256][256] W_e  L0
    const ushort_t* __restrict__ WtN1,    // [256][256] W_nb L1
    const float* __restrict__ a_e0,       // [4][256]
    const float* __restrict__ a_ed0,      // [4][256] a_edge L0
    const float* __restrict__ a_ed1,      // [4][256] a_edge L1
    const int* __restrict__ ena,          // [E][2]
    const ushort_t* __restrict__ xprojE,  // [N][256] base @ W_e(L0)
    const float* __restrict__ xan,        // [N][4]   base . a_n(L0)
    ushort_t* __restrict__ eproj0, float* __restrict__ sed0,
    ushort_t* __restrict__ eprojL1, float* __restrict__ sed1) {
  __shared__ __align__(16) char smem[32768 + 16384 + 8192 + 4096 + 1024 + 2048 + 512];
  char* sEc            = smem;                              // [64][256] bf16, XOR-swizzled
  ushort_t (*sB)[32]   = (ushort_t(*)[32])(smem + 32768);   // [256][32]
  ushort_t (*sAe)[256] = (ushort_t(*)[256])(smem + 49152);  // [16][256] score B-tile
  ushort_t (*sT)[32]   = (ushort_t(*)[32])(smem + 57344);   // [64][32]  A-stage / Y-tile
  float* sSea          = (float*)(smem + 61440);            // [64][4]
  float (*sAlp)[4][2]  = (float(*)[4][2])(smem + 62464);    // [64][4][2]
  int* sIdx            = (int*)(smem + 64512);              // [128]
  int t = threadIdx.x, w = t >> 6, l = t & 63;
  long e0 = (long)blockIdx.x * 64;

  if (t < 128) sIdx[t] = ena[e0 * 2 + t];
  {  // stage score tile: rows 0-3 = a_e(L0), rows 4-7 = a_edge(L0), rest 0
    int row = t >> 4, seg = (t & 15) * 16;
    float f[16];
    if (row < 8) {
      const float* src = (row < 4 ? a_e0 + row * 256 : a_ed0 + (row - 4) * 256) + seg;
      ld8(src, f); ld8(src + 8, f + 8);
    } else {
#pragma unroll
      for (int i = 0; i < 16; ++i) f[i] = 0.f;
    }
    *(uint4*)&sAe[row][seg] = enc8(f);
    *(uint4*)&sAe[row][seg + 8] = enc8(f + 8);
  }

  f32x4 zero = {0.f, 0.f, 0.f, 0.f};
  f32x4 acc[4][4];
#pragma unroll
  for (int mt = 0; mt < 4; ++mt)
#pragma unroll
    for (int nt = 0; nt < 4; ++nt) acc[mt][nt] = zero;

  // ---- phase 1: edgesA tile = eemb @ WtEp^T (K=64) ----
  for (int kc = 0; kc < 2; ++kc) {
    __syncthreads();
    {  // stage A chunk (f32 -> bf16)
      int r = t >> 2, ks8 = (t & 3) * 8;
      float f[8]; ld8(eemb + (e0 + r) * 64 + kc * 32 + ks8, f);
      *(uint4*)&sT[r][ks8] = enc8(f);
    }
#pragma unroll
    for (int j = 0; j < 4; ++j) {
      int u = (w * 4 + j) * 64 + l;
      int n = u >> 2, ks = u & 3;
      async16((char*)sB + (w * 4 + j) * 1024, WtEp + (long)n * 64 + kc * 32 + ks * 8);
    }
    __syncthreads();
    bf16x8 af[4], bf[4];
#pragma unroll
    for (int mt = 0; mt < 4; ++mt)
      af[mt] = *(const bf16x8*)&sT[mt * 16 + (l & 15)][(l >> 4) * 8];
#pragma unroll
    for (int nt = 0; nt < 4; ++nt)
      bf[nt] = *(const bf16x8*)&sB[w * 64 + nt * 16 + (l & 15)][(l >> 4) * 8];
#pragma unroll
    for (int mt = 0; mt < 4; ++mt)
#pragma unroll
      for (int nt = 0; nt < 4; ++nt)
        acc[mt][nt] = __builtin_amdgcn_mfma_f32_16x16x32_bf16(af[mt], bf[nt], acc[mt][nt], 0, 0, 0);
  }
  // write edgesA tile to sE (bf16, swizzled); pass A's first sync publishes it
#pragma unroll
  for (int mt = 0; mt < 4; ++mt)
#pragma unroll
    for (int nt = 0; nt < 4; ++nt)
#pragma unroll
      for (int i = 0; i < 4; ++i) {
        int row = mt * 16 + (l >> 4) * 4 + i;
        int col = w * 64 + nt * 16 + (l & 15);
        int cb = (col >> 3) ^ ((row & 7) << 2);
        *(ushort_t*)(sEc + row * 512 + cb * 16 + (col & 7) * 2) = f2b(acc[mt][nt][i]);
      }

  // ---- pass A: eproj0 = tile @ W_nb(L0); scores sea (cols 0-3) / sed0 (cols 4-7) ----
  f32x4 accs[4];
#pragma unroll
  for (int mt = 0; mt < 4; ++mt) {
    accs[mt] = zero;
#pragma unroll
    for (int nt = 0; nt < 4; ++nt) acc[mt][nt] = zero;
  }
  for (int kc = 0; kc < 8; ++kc) {
    __syncthreads();
#pragma unroll
    for (int j = 0; j < 4; ++j) {
      int u = (w * 4 + j) * 64 + l;
      int n = u >> 2, ks = u & 3;
      async16((char*)sB + (w * 4 + j) * 1024, WtN0 + (long)n * 256 + kc * 32 + ks * 8);
    }
    __syncthreads();
    bf16x8 af[4], bf[4];
#pragma unroll
    for (int mt = 0; mt < 4; ++mt) {
      int row = mt * 16 + (l & 15);
      int cb = (kc * 4 + (l >> 4)) ^ ((row & 7) << 2);
      af[mt] = *(const bf16x8*)(sEc + row * 512 + cb * 16);
    }
#pragma unroll
    for (int nt = 0; nt < 4; ++nt)
      bf[nt] = *(const bf16x8*)&sB[w * 64 + nt * 16 + (l & 15)][(l >> 4) * 8];
#pragma unroll
    for (int mt = 0; mt < 4; ++mt)
#pragma unroll
      for (int nt = 0; nt < 4; ++nt)
        acc[mt][nt] = __builtin_amdgcn_mfma_f32_16x16x32_bf16(af[mt], bf[nt], acc[mt][nt], 0, 0, 0);
    if (w == 0) {
      bf16x8 bs = *(const bf16x8*)&sAe[l & 15][kc * 32 + (l >> 4) * 8];
#pragma unroll
      for (int mt = 0; mt < 4; ++mt)
        accs[mt] = __builtin_amdgcn_mfma_f32_16x16x32_bf16(af[mt], bs, accs[mt], 0, 0, 0);
    }
  }
  __syncthreads();  // all waves done reading sAe / computing
#pragma unroll
  for (int mt = 0; mt < 4; ++mt)
#pragma unroll
    for (int nt = 0; nt < 4; ++nt)
#pragma unroll
      for (int i = 0; i < 4; ++i) {
        long row = e0 + mt * 16 + (l >> 4) * 4 + i;
        int col = w * 64 + nt * 16 + (l & 15);
        eproj0[row * 256 + col] = f2b(acc[mt][nt][i]);
      }
  if (w == 0) {
    int c = l & 15;
#pragma unroll
    for (int mt = 0; mt < 4; ++mt)
#pragma unroll
      for (int i = 0; i < 4; ++i) {
        int row = mt * 16 + (l >> 4) * 4 + i;
        float v = accs[mt][i];
        if (c < 4) sSea[row * 4 + c] = v;
        else if (c < 8) sed0[(e0 + row) * 4 + (c - 4)] = v;
      }
  }
  {  // restage score tile: rows 0-3 = a_edge(L1), rest 0
    int row = t >> 4, seg = (t & 15) * 16;
    float f[16];
    if (row < 4) {
      ld8(a_ed1 + row * 256 + seg, f);
      ld8(a_ed1 + row * 256 + seg + 8, f + 8);
    } else {
#pragma unroll
      for (int i = 0; i < 16; ++i) f[i] = 0.f;
    }
    *(uint4*)&sAe[row][seg] = enc8(f);
    *(uint4*)&sAe[row][seg + 8] = enc8(f + 8);
  }
  __syncthreads();
  {  // per-(edge,head) 2-way softmax
    int e = t >> 2, h = t & 3;
    int n0 = sIdx[2 * e], n1 = sIdx[2 * e + 1];
    float sE = sSea[e * 4 + h];
    float s0 = xan[(long)n0 * 4 + h] + sE; s0 = s0 > 0.f ? s0 : 0.2f * s0;
    float s1 = xan[(long)n1 * 4 + h] + sE; s1 = s1 > 0.f ? s1 : 0.2f * s1;
    float mx = fmaxf(s0, s1);
    float g0 = __expf(s0 - mx), g1 = __expf(s1 - mx);
    float inv = 1.f / (g0 + g1);
    sAlp[e][h][0] = g0 * inv;
    sAlp[e][h][1] = g1 * inv;
  }

  // ---- pass B: eprojE = tile @ W_e(L0), result overwrites sE ----
#pragma unroll
  for (int mt = 0; mt < 4; ++mt)
#pragma unroll
    for (int nt = 0; nt < 4; ++nt) acc[mt][nt] = zero;
  for (int kc = 0; kc < 8; ++kc) {
    __syncthreads();
#pragma unroll
    for (int j = 0; j < 4; ++j) {
      int u = (w * 4 + j) * 64 + l;
      int n = u >> 2, ks = u & 3;
      async16((char*)sB + (w * 4 + j) * 1024, WtE0 + (long)n * 256 + kc * 32 + ks * 8);
    }
    __syncthreads();
    bf16x8 af[4], bf[4];
#pragma unroll
    for (int mt = 0; mt < 4; ++mt) {
      int row = mt * 16 + (l & 15);
      int cb = (kc * 4 + (l >> 4)) ^ ((row & 7) << 2);
      af[mt] = *(const bf16x8*)(sEc + row * 512 + cb * 16);
    }
#pragma unroll
    for (int nt = 0; nt < 4; ++nt)
      bf[nt] = *(const bf16x8*)&sB[w * 64 + nt * 16 + (l & 15)][(l >> 4) * 8];
#pragma unroll
    for (int mt = 0; mt < 4; ++mt)
#pragma unroll
      for (int nt = 0; nt < 4; ++nt)
        acc[mt][nt] = __builtin_amdgcn_mfma_f32_16x16x32_bf16(af[mt], bf[nt], acc[mt][nt], 0, 0, 0);
  }
  __syncthreads();  // all reads of sE (edgesA) complete before overwrite
#pragma unroll
  for (int mt = 0; mt < 4; ++mt)
#pragma unroll
    for (int nt = 0; nt < 4; ++nt)
#pragma unroll
      for (int i = 0; i < 4; ++i) {
        int row = mt * 16 + (l >> 4) * 4 + i;
        int col = w * 64 + nt * 16 + (l & 15);
        int cb = (col >> 3) ^ ((row & 7) << 2);
        *(ushort_t*)(sEc + row * 512 + cb * 16 + (col & 7) * 2) = f2b(acc[mt][nt][i]);
      }

  // ---- phase 3: combine + @ W_nb(L1) ----
#pragma unroll
  for (int mt = 0; mt < 4; ++mt) {
    accs[mt] = zero;
#pragma unroll
    for (int nt = 0; nt < 4; ++nt) acc[mt][nt] = zero;
  }
  int r3 = t >> 2, cq = t & 3;
  int n0r = sIdx[2 * r3], n1r = sIdx[2 * r3 + 1];
  const ushort_t* p0 = xprojE + (long)n0r * 256 + cq * 8;
  const ushort_t* p1 = xprojE + (long)n1r * 256 + cq * 8;
  float a0h[4], a1h[4];
#pragma unroll
  for (int h = 0; h < 4; ++h) { a0h[h] = sAlp[r3][h][0]; a1h[h] = sAlp[r3][h][1]; }
  for (int kc = 0; kc < 8; ++kc) {
    __syncthreads();  // publishes sE overwrite (kc=0); guards sT/sB reuse
#pragma unroll
    for (int j = 0; j < 4; ++j) {
      int u = (w * 4 + j) * 64 + l;
      int n = u >> 2, ks = u & 3;
      async16((char*)sB + (w * 4 + j) * 1024, WtN1 + (long)n * 256 + kc * 32 + ks * 8);
    }
    {  // build Y tile (head h = kc>>1)
      int h = kc >> 1;
      int cb = (kc * 4 + cq) ^ ((r3 & 7) << 2);
      float ep[8], x0[8], x1[8], y[8];
      dec8(*(const uint4*)(sEc + r3 * 512 + cb * 16), ep);
      dec8(*(const uint4*)(p0 + kc * 32), x0);
      dec8(*(const uint4*)(p1 + kc * 32), x1);
#pragma unroll
      for (int d = 0; d < 8; ++d) {
        float v = ep[d] + a0h[h] * x0[d] + a1h[h] * x1[d];
        y[d] = ELUF(v);
      }
      *(uint4*)&sT[r3][cq * 8] = enc8(y);
    }
    __syncthreads();
    bf16x8 af[4], bf[4];
#pragma unroll
    for (int mt = 0; mt < 4; ++mt)
      af[mt] = *(const bf16x8*)&sT[mt * 16 + (l & 15)][(l >> 4) * 8];
#pragma unroll
    for (int nt = 0; nt < 4; ++nt)
      bf[nt] = *(const bf16x8*)&sB[w * 64 + nt * 16 + (l & 15)][(l >> 4) * 8];
#pragma unroll
    for (int mt = 0; mt < 4; ++mt)
#pragma unroll
      for (int nt = 0; nt < 4; ++nt)
        acc[mt][nt] = __builtin_amdgcn_mfma_f32_16x16x32_bf16(af[mt], bf[nt], acc[mt][nt], 0, 0, 0);
    if (w == 0) {  // fused sed1
      bf16x8 bs = *(const bf16x8*)&sAe[l & 15][kc * 32 + (l >> 4) * 8];
#pragma unroll
      for (int mt = 0; mt < 4; ++mt)
        accs[mt] = __builtin_amdgcn_mfma_f32_16x16x32_bf16(af[mt], bs, accs[mt], 0, 0, 0);
    }
  }
#pragma unroll
  for (int mt = 0; mt < 4; ++mt)
#pragma unroll
    for (int nt = 0; nt < 4; ++nt)
#pragma unroll
      for (int i = 0; i < 4; ++i) {
        long row = e0 + mt * 16 + (l >> 4) * 4 + i;
        int col = w * 64 + nt * 16 + (l & 15);
        eprojL1[row * 256 + col] = f2b(acc[mt][nt][i]);
      }
  if (w == 0 && (l & 15) < 4) {
#pragma unroll
    for (int mt = 0; mt < 4; ++mt)
#pragma unroll
      for (int i = 0; i < 4; ++i) {
        long row = e0 + mt * 16 + (l >> 4) * 4 + i;
        sed1[row * 4 + (l & 15)] = accs[mt][i];
      }
  }
}

// ---------- fused node layer: out = elu(xin@W_self + sum_k alpha_k * eproj[e_k]) ----------
__global__ __launch_bounds__(256, 2) void node_out(
    const ushort_t* __restrict__ xb,     // bf16 [N][256] (xin)
    const int* __restrict__ n2e,         // [N][8]
    const ushort_t* __restrict__ eproj,  // bf16 [E][256]
    const float* __restrict__ sed,       // f32 [E][4]
    const float* __restrict__ a_s,       // f32 [4][256]
    const ushort_t* __restrict__ WtS,    // bf16 [256][256]
    float* __restrict__ outp,            // f32, row stride 512
    ushort_t* __restrict__ xout) {       // bf16 [N][256] or nullptr
  __shared__ __align__(16) char smem[33280 + 1024 + 4096 + 4096];
  ushort_t (*sX)[32]   = (ushort_t(*)[32])smem;            // [32][32]   (K-loop)
  ushort_t (*sBs)[32]  = (ushort_t(*)[32])(smem + 2048);   // [256][32]  (K-loop)
  ushort_t (*sAs)[256] = (ushort_t(*)[256])(smem + 18432); // [4][256]   (K-loop)
  float* sOutF         = (float*)smem;                      // overlay [32][260] f32 (33280B)
  int*   sIdx          = (int*)(smem + 33280);              // [256]
  float* sSe           = (float*)(smem + 34304);            // [256][4]
  float* sAln          = (float*)(smem + 38400);            // [32][4][8]
  int t = threadIdx.x, w = t >> 6, l = t & 63;
  long n0 = (long)blockIdx.x * 32;

  {  // prologue: edge ids + score gather
    int e = n2e[n0 * 8 + t];
    sIdx[t] = e;
    *(float4*)&sSe[t * 4] = *(const float4*)(sed + (long)e * 4);
  }
  if (t < 128) {  // stage a_s as bf16
    int row = t >> 5, dof = (t & 31) * 8;
    float f[8]; ld8(a_s + row * 256 + dof, f);
    *(uint4*)&sAs[row][dof] = enc8(f);
  }

  f32x4 zero = {0.f, 0.f, 0.f, 0.f};
  f32x4 acc[2][4];
#pragma unroll
  for (int mt = 0; mt < 2; ++mt)
#pragma unroll
    for (int nt = 0; nt < 4; ++nt) acc[mt][nt] = zero;
  float ssp = 0.f;
  int sn = t >> 3, shalf = (t & 1) * 16, sh = (t >> 1) & 3;

  for (int kc = 0; kc < 8; ++kc) {
    __syncthreads();
    if (w == 0) {
#pragma unroll
      for (int j = 0; j < 2; ++j) {
        int u = j * 64 + l;
        int r = u >> 2, ks = u & 3;
        async16((char*)sX + j * 1024, xb + (n0 + r) * 256 + kc * 32 + ks * 8);
      }
    }
#pragma unroll
    for (int j = 0; j < 4; ++j) {
      int u = (w * 4 + j) * 64 + l;
      int n = u >> 2, ks = u & 3;
      async16((char*)sBs + (w * 4 + j) * 1024, WtS + (long)n * 256 + kc * 32 + ks * 8);
    }
    __syncthreads();
    bf16x8 ax[2], bs[4];
#pragma unroll
    for (int mt = 0; mt < 2; ++mt)
      ax[mt] = *(const bf16x8*)&sX[mt * 16 + (l & 15)][(l >> 4) * 8];
#pragma unroll
    for (int nt = 0; nt < 4; ++nt)
      bs[nt] = *(const bf16x8*)&sBs[w * 64 + nt * 16 + (l & 15)][(l >> 4) * 8];
#pragma unroll
    for (int mt = 0; mt < 2; ++mt)
#pragma unroll
      for (int nt = 0; nt < 4; ++nt)
        acc[mt][nt] = __builtin_amdgcn_mfma_f32_16x16x32_bf16(ax[mt], bs[nt], acc[mt][nt], 0, 0, 0);
    {  // fused ss partial: thread (node sn, head sh, half) does 16 dims
      float xv[16], av[16];
      dec8(*(const uint4*)&sX[sn][shalf], xv);
      dec8(*(const uint4*)&sX[sn][shalf + 8], xv + 8);
      dec8(*(const uint4*)&sAs[sh][kc * 32 + shalf], av);
      dec8(*(const uint4*)&sAs[sh][kc * 32 + shalf + 8], av + 8);
#pragma unroll
      for (int d = 0; d < 16; ++d) ssp += xv[d] * av[d];
    }
  }
  __syncthreads();
#pragma unroll
  for (int mt = 0; mt < 2; ++mt)
#pragma unroll
    for (int nt = 0; nt < 4; ++nt)
#pragma unroll
      for (int i = 0; i < 4; ++i) {
        int row = mt * 16 + (l >> 4) * 4 + i;
        int col = w * 64 + nt * 16 + (l & 15);
        sOutF[row * 260 + col] = acc[mt][nt][i];
      }
  float ssv = ssp + __shfl_xor(ssp, 1, 64);
  if (!(t & 1)) {
    float sv[8], mx = -1e30f;
#pragma unroll
    for (int k = 0; k < 8; ++k) {
      float s = ssv + sSe[(sn * 8 + k) * 4 + sh];
      s = s > 0.f ? s : 0.2f * s;
      sv[k] = s; mx = fmaxf(mx, s);
    }
    float sum = 0.f;
#pragma unroll
    for (int k = 0; k < 8; ++k) { sv[k] = __expf(sv[k] - mx); sum += sv[k]; }
    float inv = 1.f / sum;
#pragma unroll
    for (int k = 0; k < 8; ++k) sAln[(sn * 4 + sh) * 8 + k] = sv[k] * inv;
  }
  __syncthreads();

  int nT = t >> 3, sT = t & 7, hh = sT >> 1, dof = sT * 32;
  float wts[8];
#pragma unroll
  for (int k = 0; k < 8; ++k) wts[k] = sAln[(nT * 4 + hh) * 8 + k];
  int eidx[8];
#pragma unroll
  for (int k = 0; k < 8; ++k) eidx[k] = sIdx[nT * 8 + k];
  float o[32];
#pragma unroll
  for (int j = 0; j < 8; ++j) {
    float4 sv = *(const float4*)&sOutF[nT * 260 + dof + j * 4];
    o[j * 4 + 0] = sv.x; o[j * 4 + 1] = sv.y; o[j * 4 + 2] = sv.z; o[j * 4 + 3] = sv.w;
  }
#pragma unroll
  for (int k = 0; k < 8; ++k) {
    const ushort_t* pr = eproj + (long)eidx[k] * 256 + dof;
    float v[32];
    dec8(*(const uint4*)(pr),      v);
    dec8(*(const uint4*)(pr + 8),  v + 8);
    dec8(*(const uint4*)(pr + 16), v + 16);
    dec8(*(const uint4*)(pr + 24), v + 24);
    float wk = wts[k];
#pragma unroll
    for (int d = 0; d < 32; ++d) o[d] += wk * v[d];
  }
  long row = n0 + nT;
  float res[32];
#pragma unroll
  for (int d = 0; d < 32; ++d) res[d] = ELUF(o[d]);
  float* po = outp + row * 512 + dof;
#pragma unroll
  for (int j = 0; j < 8; ++j) {
    float4 q;
    q.x = res[j * 4 + 0]; q.y = res[j * 4 + 1]; q.z = res[j * 4 + 2]; q.w = res[j * 4 + 3];
    *(float4*)(po + j * 4) = q;
  }
  if (xout) {
#pragma unroll
    for (int j = 0; j < 4; ++j)
      *(uint4*)(xout + row * 256 + dof + j * 8) = enc8(res + j * 8);
  }
}

extern "C" void kernel_launch(void* const* d_in, const int* in_sizes, int n_in,
                              void* d_out, int out_size, void* d_ws, size_t ws_size,
                              hipStream_t stream) {
  (void)in_sizes; (void)n_in; (void)out_size; (void)ws_size;
  const float* feats  = (const float*)d_in[0];
  const float* eemb   = (const float*)d_in[1];
  const int*   adj    = (const int*)d_in[2];
  const int*   n2e    = (const int*)d_in[3];
  const float* Wp0    = (const float*)d_in[4];
  const float* Wp1    = (const float*)d_in[5];
  const float* Wep    = (const float*)d_in[6];
  const float* a_e    = (const float*)d_in[7];
  const float* a_n    = (const float*)d_in[8];
  const float* W_e    = (const float*)d_in[9];
  const float* a_s    = (const float*)d_in[10];
  const float* a_edge = (const float*)d_in[11];
  const float* W_self = (const float*)d_in[12];
  const float* W_nb   = (const float*)d_in[13];
  float* out = (float*)d_out;

  // workspace carve (~360 MiB)
  char* w = (char*)d_ws;
  ushort_t* dummy_bf = (ushort_t*)w; w += (size_t)N_NODES * 256 * 2;
  ushort_t* base_bf  = (ushort_t*)w; w += (size_t)N_NODES * 256 * 2;
  ushort_t* eproj0   = (ushort_t*)w; w += (size_t)N_EDGES * 256 * 2;
  ushort_t* eprojL1  = (ushort_t*)w; w += (size_t)N_EDGES * 256 * 2;
  ushort_t* bufX     = (ushort_t*)w; w += (size_t)N_NODES * 256 * 2;  // xprojE then xl1
  float*    sed0     = (float*)w;    w += (size_t)N_EDGES * 4 * 4;
  float*    sed1     = (float*)w;    w += (size_t)N_EDGES * 4 * 4;
  float*    xan      = (float*)w;    w += (size_t)N_NODES * 4 * 4;
  ushort_t* WtP0     = (ushort_t*)w; w += 256 * 256 * 2;
  ushort_t* WtP1     = (ushort_t*)w; w += 256 * 256 * 2;
  ushort_t* WtEp     = (ushort_t*)w; w += 2 * 256 * 64 * 2;
  ushort_t* WtE      = (ushort_t*)w; w += 16 * 16384 * 2;
  ushort_t* WtS      = (ushort_t*)w; w += 16 * 16384 * 2;
  ushort_t* WtN      = (ushort_t*)w; w += 16 * 16384 * 2;

  // weight pre-transpose to bf16 Wt[n][k]
  wt_kernel<<<dim3(256, 1), 256, 0, stream>>>(Wp0, WtP0, 256, 256);
  wt_kernel<<<dim3(256, 1), 256, 0, stream>>>(Wp1, WtP1, 256, 256);
  wt_kernel<<<dim3(64, 2), 256, 0, stream>>>(Wep, WtEp, 64, 256);
  wt_kernel<<<dim3(64, 16), 256, 0, stream>>>(W_e, WtE, 256, 64);
  wt_kernel<<<dim3(64, 16), 256, 0, stream>>>(W_self, WtS, 256, 64);
  wt_kernel<<<dim3(64, 16), 256, 0, stream>>>(W_nb, WtN, 256, 64);

  // prep: dummy_bf = feats@Wp0, base_bf = feats@Wp1 in one pass over feats
  gemm_mfma2<<<N_NODES / 64, 256, 0, stream>>>(feats, WtP0, WtP1, dummy_bf, base_bf);

  for (int mp = 0; mp < 2; ++mp) {
    const int* adj_mp = adj + (size_t)mp * N_EDGES * 2;
    const int* n2e_mp = n2e + (size_t)mp * N_NODES * 8;
    size_t ao0 = (size_t)(mp * 2 + 0) * 1024, ao1 = (size_t)(mp * 2 + 1) * 1024;
    size_t wo0 = (size_t)(mp * 2 + 0) * 65536, wo1 = (size_t)(mp * 2 + 1) * 65536;

    ushort_t* xprojE = bufX;
    ushort_t* xl1    = bufX;  // alias: xprojE dead after edge_mega

    // 1. xprojE = base @ W_e(L0), xan = base . a_n(L0)
    gemm_eproj<<<N_NODES / 64, 256, 0, stream>>>(base_bf, WtE + wo0, a_n + ao0, xprojE, xan);
    // 2. whole edge pipeline: eproj0+sed0 (L0 node inputs), eprojL1+sed1 (L1 node inputs)
    edge_mega<<<N_EDGES / 64, 256, 0, stream>>>(
        eemb + (size_t)mp * N_EDGES * 64, WtEp + (size_t)mp * 16384,
        WtN + wo0, WtE + wo0, WtN + wo1,
        a_e + ao0, a_edge + ao0, a_edge + ao1,
        adj_mp, xprojE, xan, eproj0, sed0, eprojL1, sed1);
    // 3. node layer 0 (xin = dummy prep)
    node_out<<<N_NODES / 32, 256, 0, stream>>>(dummy_bf, n2e_mp, eproj0, sed0,
                                               a_s + ao0, WtS + wo0,
                                               out + (size_t)mp * N_NODES * 512, xl1);
    // 4. node layer 1
    node_out<<<N_NODES / 32, 256, 0, stream>>>(xl1, n2e_mp, eprojL1, sed1,
                                               a_s + ao1, WtS + wo1,
                                               out + (size_t)mp * N_NODES * 512 + 256,
                                               (ushort_t*)nullptr);
  }
}